// Round 8
// baseline (43579.617 us; speedup 1.0000x reference)
//
#include <hip/hip_runtime.h>

// ---------------------------------------------------------------------------
// GRANGER — R8: FP32 OUTPUTS. The reference returns jnp.float32 tensors, so
// d_out is an fp32 buffer ("the reference's OUTPUT dtype"); R0-R7 wrote bf16
// u16s into it (the "(bf16" in the test label is a baked literal, not the
// runtime dtype). Scalar verified structure from R6/R7; input dtype probed
// on-device (R7 probe confirmed fp32 inputs).
// Output layout (fp32): pred[P,B,L,1] | log_var[B,H] | mu[B,H] | mean_[B,P]
// | disp_[B,P]
// ---------------------------------------------------------------------------

#define OFF_LV   409600
#define OFF_MU   425984
#define OFF_MEAN 442368
#define OFF_DISP 446464

__device__ __forceinline__ float bf2f(unsigned short u) {
    union { unsigned int i; float f; } v; v.i = ((unsigned int)u) << 16; return v.f;
}
__device__ __forceinline__ float sigm(float x) {
    return 1.0f / (1.0f + expf(-x));
}

// load float element i from array p whose storage dtype is BF ? bf16 : fp32
template <bool BF>
__device__ __forceinline__ float ldf(const void* p, size_t i) {
    if (BF) return bf2f(((const unsigned short*)p)[i]);
    else    return ((const float*)p)[i];
}

// Probe storage dtype of N(0,sigma)-distributed float data: bf16 u16s have
// plausible exponent fields (~100% in [110,135]); fp32 even-u16s are low
// mantissa halves (uniform, ~10%). Deterministic, uniform across blocks.
__device__ __forceinline__ bool probe_bf16(const void* X) {
    const unsigned short* u = (const unsigned short*)X;
    int c = 0;
    #pragma unroll
    for (int i = 0; i < 128; i += 2) {
        int e = (u[i] >> 7) & 0xFF;
        c += (e >= 110 && e <= 135) ? 1 : 0;
    }
    return c >= 32;
}

// ---------------------------------------------------------------------------
// Encoder body: one block per batch row b, 256 threads (one per hidden j).
// ---------------------------------------------------------------------------
template <bool BF>
__device__ void encoder_body(
    const void* X,    const void* Wihl, const void* Whhl,
    const void* bihl, const void* bhhl,
    const void* Wih1, const void* bih1, const void* bhh1,
    const void* Wmu,  const void* bmu,  const void* Wstd, const void* bstd,
    const void* Wmean,const void* bmean,const void* Wdisp,const void* bdisp,
    float* out, float* h, float* xt)
{
    const int b = blockIdx.x;
    const int j = threadIdx.x;

    h[j] = 0.f;
    __syncthreads();

    // ---- gru_left: 10 steps over X[:, 0:10, :] (= X_pad[:, 1:11, :]) ----
    for (int t = 0; t < 10; t++) {
        if (j < 64) xt[j] = ldf<BF>(X, (size_t)(b * 110 + t) * 64 + j);
        __syncthreads();                       // xt + h visible

        float gr = ldf<BF>(bihl, j);
        float gz = ldf<BF>(bihl, 256 + j);
        float gn = ldf<BF>(bihl, 512 + j);
        for (int k = 0; k < 64; k++) {
            float x = xt[k];
            gr += ldf<BF>(Wihl, (size_t)j * 64 + k) * x;
            gz += ldf<BF>(Wihl, (size_t)(256 + j) * 64 + k) * x;
            gn += ldf<BF>(Wihl, (size_t)(512 + j) * 64 + k) * x;
        }
        float hr = ldf<BF>(bhhl, j);
        float hz = ldf<BF>(bhhl, 256 + j);
        float hn = ldf<BF>(bhhl, 512 + j);
        for (int k = 0; k < 256; k++) {
            float hv = h[k];
            hr += ldf<BF>(Whhl, (size_t)j * 256 + k) * hv;
            hz += ldf<BF>(Whhl, (size_t)(256 + j) * 256 + k) * hv;
            hn += ldf<BF>(Whhl, (size_t)(512 + j) * 256 + k) * hv;
        }
        float r    = sigm(gr + hr);
        float zg   = sigm(gz + hz);
        float nn   = tanhf(gn + r * hn);
        float hnew = (1.f - zg) * nn + zg * h[j];
        __syncthreads();                       // all h/xt reads complete
        h[j] = hnew;
    }
    __syncthreads();                           // h = h_left visible

    // ---- gru_1: single step, input h_left, hidden 0 (gh = b_hh_1) ----
    {
        float gr = ldf<BF>(bih1, j);
        float gz = ldf<BF>(bih1, 256 + j);
        float gn = ldf<BF>(bih1, 512 + j);
        for (int k = 0; k < 256; k++) {
            float hv = h[k];
            gr += ldf<BF>(Wih1, (size_t)j * 256 + k) * hv;
            gz += ldf<BF>(Wih1, (size_t)(256 + j) * 256 + k) * hv;
            gn += ldf<BF>(Wih1, (size_t)(512 + j) * 256 + k) * hv;
        }
        float r  = sigm(gr + ldf<BF>(bhh1, j));
        float zg = sigm(gz + ldf<BF>(bhh1, 256 + j));
        float nn = tanhf(gn + r * ldf<BF>(bhh1, 512 + j));
        float h1v = (1.f - zg) * nn;           // + zg * 0
        __syncthreads();                       // all h_left reads complete
        h[j] = h1v;                            // h = h1
        __syncthreads();
    }

    // ---- heads (fp32 straight to out) ----
    {
        float mu = ldf<BF>(bmu, j);
        float lv = ldf<BF>(bstd, j);
        for (int k = 0; k < 256; k++) {
            float hv = h[k];
            mu += ldf<BF>(Wmu,  (size_t)j * 256 + k) * hv;
            lv += ldf<BF>(Wstd, (size_t)j * 256 + k) * hv;
        }
        out[OFF_MU + b * 256 + j] = mu;
        out[OFF_LV + b * 256 + j] = lv;
    }
    if (j < 64) {
        float me = ldf<BF>(bmean, j);
        float dp = ldf<BF>(bdisp, j);
        for (int k = 0; k < 256; k++) {
            float hv = h[k];
            me += ldf<BF>(Wmean, (size_t)j * 256 + k) * hv;
            dp += ldf<BF>(Wdisp, (size_t)j * 256 + k) * hv;
        }
        me = fminf(fmaxf(expf(me), 1e-5f), 1e6f);                 // MeanAct
        float sp = (dp > 20.f) ? dp : log1pf(expf(dp));           // softplus
        sp = fminf(fmaxf(sp, 1e-4f), 1e4f);                       // DispAct
        out[OFF_MEAN + b * 64 + j] = me;
        out[OFF_DISP + b * 64 + j] = sp;
    }
}

__global__ __launch_bounds__(256) void encoder_k(
    const void* X,    const void* Wihl, const void* Whhl,
    const void* bihl, const void* bhhl,
    const void* Wih1, const void* bih1, const void* bhh1,
    const void* Wmu,  const void* bmu,  const void* Wstd, const void* bstd,
    const void* Wmean,const void* bmean,const void* Wdisp,const void* bdisp,
    float* out)
{
    __shared__ float h[256];
    __shared__ float xt[64];
    if (probe_bf16(X))
        encoder_body<true>(X, Wihl, Whhl, bihl, bhhl, Wih1, bih1, bhh1,
                           Wmu, bmu, Wstd, bstd, Wmean, bmean, Wdisp, bdisp,
                           out, h, xt);
    else
        encoder_body<false>(X, Wihl, Whhl, bihl, bhhl, Wih1, bih1, bhh1,
                            Wmu, bmu, Wstd, bstd, Wmean, bmean, Wdisp, bdisp,
                            out, h, xt);
}

// ---------------------------------------------------------------------------
// Nets body: grid (p=64, 16 batch-tiles of 4 rows), 256 threads (one per
// hidden j). z = mu + exp(0.5*lv)*noise re-read from out's FP32 mu/lv.
// ---------------------------------------------------------------------------
template <bool BF>
__device__ void nets_body(
    const void* X, const int* __restrict__ conn,
    const void* Wihn, const void* Whhn, const void* bihn, const void* bhhn,
    const void* Wlin, const void* blin, const void* znoise,
    float* out,
    float (*h)[256], float (*xt)[16], float (*pp)[256])
{
    const int p  = blockIdx.x;
    const int b0 = blockIdx.y * 4;
    const int j  = threadIdx.x;

    for (int bb = 0; bb < 4; bb++) {
        int gi = (b0 + bb) * 256 + j;
        float m  = out[OFF_MU + gi];
        float lv = out[OFF_LV + gi];
        h[bb][j] = m + expf(0.5f * lv) * ldf<BF>(znoise, gi);
    }
    if (j < 64) xt[j >> 4][j & 15] = 0.f;   // l=0 input is the zero pad
    __syncthreads();

    const size_t pb = (size_t)p * 768;
    const float bir  = ldf<BF>(bihn, pb + j);
    const float biz  = ldf<BF>(bihn, pb + 256 + j);
    const float bin_ = ldf<BF>(bihn, pb + 512 + j);
    const float bhr  = ldf<BF>(bhhn, pb + j);
    const float bhz  = ldf<BF>(bhhn, pb + 256 + j);
    const float bhn  = ldf<BF>(bhhn, pb + 512 + j);
    const float wl   = ldf<BF>(Wlin, (size_t)p * 256 + j);
    const size_t wi0 = (pb + j) * 16,  wi1 = (pb + 256 + j) * 16,  wi2 = (pb + 512 + j) * 16;
    const size_t wh0 = (pb + j) * 256, wh1 = (pb + 256 + j) * 256, wh2 = (pb + 512 + j) * 256;

    for (int t = 0; t < 100; t++) {
        float hnew[4];
        for (int bb = 0; bb < 4; bb++) {
            float gr = bir, gz = biz, gn = bin_;
            for (int k = 0; k < 16; k++) {
                float x = xt[bb][k];
                gr += ldf<BF>(Wihn, wi0 + k) * x;
                gz += ldf<BF>(Wihn, wi1 + k) * x;
                gn += ldf<BF>(Wihn, wi2 + k) * x;
            }
            float hr = bhr, hz = bhz, hn = bhn;
            for (int k = 0; k < 256; k++) {
                float hv = h[bb][k];
                hr += ldf<BF>(Whhn, wh0 + k) * hv;
                hz += ldf<BF>(Whhn, wh1 + k) * hv;
                hn += ldf<BF>(Whhn, wh2 + k) * hv;
            }
            float r  = sigm(gr + hr);
            float zg = sigm(gz + hz);
            float nn = tanhf(gn + r * hn);
            hnew[bb] = (1.f - zg) * nn + zg * h[bb][j];
        }
        __syncthreads();                    // all h/xt reads complete

        for (int bb = 0; bb < 4; bb++) {
            h[bb][j]  = hnew[bb];
            pp[bb][j] = fmaxf(hnew[bb], 0.f) * wl;
        }
        if (j < 64) {                       // prefetch x for step t+1
            int bb = j >> 4, k = j & 15;
            xt[bb][k] = (t < 99)
                ? ldf<BF>(X, (size_t)((b0 + bb) * 110 + (10 + t)) * 64 + conn[p * 16 + k])
                : 0.f;
        }
        __syncthreads();                    // h/pp/xt writes visible

        if (j < 4) {
            float s = ldf<BF>(blin, p);
            for (int k = 0; k < 256; k++) s += pp[j][k];
            out[(size_t)(p * 64 + b0 + j) * 100 + t] = s;
        }
        // pp stable while j<4 read: next pp write is after next iter's first
        // barrier, which readers reach only after their reads.
    }
}

__global__ __launch_bounds__(256) void nets_k(
    const void* X, const int* __restrict__ conn,
    const void* Wihn, const void* Whhn, const void* bihn, const void* bhhn,
    const void* Wlin, const void* blin, const void* znoise,
    float* out)
{
    __shared__ float h[4][256];
    __shared__ float xt[4][16];
    __shared__ float pp[4][256];
    if (probe_bf16(X))
        nets_body<true>(X, conn, Wihn, Whhn, bihn, bhhn, Wlin, blin, znoise,
                        out, h, xt, pp);
    else
        nets_body<false>(X, conn, Wihn, Whhn, bihn, bhhn, Wlin, blin, znoise,
                         out, h, xt, pp);
}

// ---------------------------------------------------------------------------
extern "C" void kernel_launch(void* const* d_in, const int* in_sizes, int n_in,
                              void* d_out, int out_size, void* d_ws, size_t ws_size,
                              hipStream_t stream) {
    const void* X      = d_in[0];
    const int*  conn   = (const int*)d_in[1];
    const void* Wihl   = d_in[2];
    const void* Whhl   = d_in[3];
    const void* bihl   = d_in[4];
    const void* bhhl   = d_in[5];
    const void* Wih1   = d_in[6];
    // d_in[7] = W_hh_1 unused: gru_1's h0 is 0, so gh reduces to b_hh_1
    const void* bih1   = d_in[8];
    const void* bhh1   = d_in[9];
    const void* Wmu    = d_in[10];
    const void* bmu    = d_in[11];
    const void* Wstd   = d_in[12];
    const void* bstd   = d_in[13];
    const void* Wmean  = d_in[14];
    const void* bmean  = d_in[15];
    const void* Wdisp  = d_in[16];
    const void* bdisp  = d_in[17];
    const void* Wihn   = d_in[18];
    const void* Whhn   = d_in[19];
    const void* bihn   = d_in[20];
    const void* bhhn   = d_in[21];
    const void* Wlin   = d_in[22];
    const void* blin   = d_in[23];
    const void* znoise = d_in[24];

    float* out = (float*)d_out;
    (void)d_ws; (void)ws_size;

    encoder_k<<<64, 256, 0, stream>>>(
        X, Wihl, Whhl, bihl, bhhl, Wih1, bih1, bhh1,
        Wmu, bmu, Wstd, bstd, Wmean, bmean, Wdisp, bdisp, out);

    nets_k<<<dim3(64, 16), 256, 0, stream>>>(
        X, conn, Wihn, Whhn, bihn, bhhn, Wlin, blin, znoise, out);
}

// Round 9
// 2247.244 us; speedup vs baseline: 19.3925x; 19.3925x over previous
//
#include <hip/hip_runtime.h>

// ---------------------------------------------------------------------------
// GRANGER — R9: MFMA nets kernel (fp32 in, fp32 out).
// R8 root cause: outputs are fp32 (ref returns jnp.float32). Scalar R8 passed
// at 43.6 ms, FETCH 44 GB (weight re-reads). This round: one block per p
// (64 blocks, 1024 thr, 16 waves, all 64 batch rows) -> W_hh[p] read once
// per step from L2 (bf16 copy pre-converted into d_ws); gates via
// mfma_f32_16x16x32_bf16 (layouts per guide m89/m91); h carried fp32 in
// registers, bf16 only as MFMA operand.
// Output layout (fp32): pred[P,B,L,1] | log_var[B,H] | mu[B,H] | mean_[B,P]
// | disp_[B,P]
// ---------------------------------------------------------------------------

#define OFF_LV   409600
#define OFF_MU   425984
#define OFF_MEAN 442368
#define OFF_DISP 446464

typedef __attribute__((ext_vector_type(8))) short  bf16x8;
typedef __attribute__((ext_vector_type(4))) float  f32x4;

__device__ __forceinline__ float bf2f(unsigned short u) {
    union { unsigned int i; float f; } v; v.i = ((unsigned int)u) << 16; return v.f;
}
__device__ __forceinline__ unsigned short f2bf(float f) {
    union { float f; unsigned int i; } v; v.f = f;
    unsigned int x = v.i;
    return (unsigned short)((x + 0x7FFFu + ((x >> 16) & 1u)) >> 16);
}
__device__ __forceinline__ unsigned short f2bf_fast(float f) {
    return (unsigned short)((__float_as_uint(f) + 0x8000u) >> 16);
}
// pack 8 consecutive fp32 -> bf16x8
__device__ __forceinline__ bf16x8 pack8(const float* pf) {
    union { unsigned int u[4]; bf16x8 v; } r;
    const float4 a = *(const float4*)pf;
    const float4 b = *(const float4*)(pf + 4);
    r.u[0] = ((__float_as_uint(a.x) + 0x8000u) >> 16) | ((__float_as_uint(a.y) + 0x8000u) & 0xFFFF0000u);
    r.u[1] = ((__float_as_uint(a.z) + 0x8000u) >> 16) | ((__float_as_uint(a.w) + 0x8000u) & 0xFFFF0000u);
    r.u[2] = ((__float_as_uint(b.x) + 0x8000u) >> 16) | ((__float_as_uint(b.y) + 0x8000u) & 0xFFFF0000u);
    r.u[3] = ((__float_as_uint(b.z) + 0x8000u) >> 16) | ((__float_as_uint(b.w) + 0x8000u) & 0xFFFF0000u);
    return r.v;
}
__device__ __forceinline__ float sigm(float x) {
    return 1.0f / (1.0f + __expf(-x));
}
__device__ __forceinline__ float tanh_fast(float x) {
    return 2.0f / (1.0f + __expf(-2.0f * x)) - 1.0f;
}

#define MFMA(a, b, c) __builtin_amdgcn_mfma_f32_16x16x32_bf16((a), (b), (c), 0, 0, 0)

// ---------------------------------------------------------------------------
// W_hh fp32 -> bf16 (row-major, same indexing) into d_ws.
// ---------------------------------------------------------------------------
__global__ __launch_bounds__(256) void cvt_whh_kernel(
    const float* __restrict__ src, unsigned short* __restrict__ dst, int n4)
{
    int i = blockIdx.x * 256 + threadIdx.x;   // one thread = 4 elements
    if (i < n4) {
        float4 a = ((const float4*)src)[i];
        ushort4 r;
        r.x = f2bf_fast(a.x); r.y = f2bf_fast(a.y);
        r.z = f2bf_fast(a.z); r.w = f2bf_fast(a.w);
        ((ushort4*)dst)[i] = r;
    }
}

// ---------------------------------------------------------------------------
// Encoder: one block per batch row b, 768 threads (one per gate row).
// fp32 in / fp32 out. (R4 structure, validated semantics per R8.)
// ---------------------------------------------------------------------------
__global__ __launch_bounds__(768) void encoder_kernel(
    const float* __restrict__ X,      // (64,110,64)
    const float* __restrict__ Wihl,   // (768,64)
    const float* __restrict__ Whhl,   // (768,256)
    const float* __restrict__ bihl,   // (768)
    const float* __restrict__ bhhl,   // (768)
    const float* __restrict__ Wih1,   // (768,256)
    const float* __restrict__ bih1,   // (768)
    const float* __restrict__ bhh1,   // (768)
    const float* __restrict__ Wmu,    // (256,256)
    const float* __restrict__ bmu,    // (256)
    const float* __restrict__ Wstd,   // (256,256)
    const float* __restrict__ bstd,   // (256)
    const float* __restrict__ Wmean,  // (64,256)
    const float* __restrict__ bmean,  // (64)
    const float* __restrict__ Wdisp,  // (64,256)
    const float* __restrict__ bdisp,  // (64)
    float* __restrict__ out)
{
    const int b   = blockIdx.x;
    const int tid = threadIdx.x;

    __shared__ float h[256];
    __shared__ float xv[64];
    __shared__ float gates[768];
    __shared__ float hn[256];

    if (tid < 256) h[tid] = 0.f;

    // ---- gru_left over X[:,0:10,:] (= X_pad[:,1:11,:]) ----
    for (int t = 0; t < 10; t++) {
        if (tid < 64) xv[tid] = X[(b * 110 + t) * 64 + tid];
        __syncthreads();   // xv + h visible

        float si = bihl[tid];
        const float* wi = Wihl + tid * 64;
        #pragma unroll 4
        for (int k = 0; k < 64; k += 4) {
            float4 w4 = *(const float4*)(wi + k);
            si += w4.x * xv[k] + w4.y * xv[k+1] + w4.z * xv[k+2] + w4.w * xv[k+3];
        }
        float sh = bhhl[tid];
        const float* wh = Whhl + tid * 256;
        #pragma unroll 4
        for (int k = 0; k < 256; k += 4) {
            float4 w4 = *(const float4*)(wh + k);
            sh += w4.x * h[k] + w4.y * h[k+1] + w4.z * h[k+2] + w4.w * h[k+3];
        }
        if (tid < 512) gates[tid] = si + sh;
        else { gates[tid] = si; hn[tid & 255] = sh; }
        __syncthreads();   // gates visible, all h reads done

        if (tid < 256) {
            float r  = sigm(gates[tid]);
            float zg = sigm(gates[256 + tid]);
            float nn = tanh_fast(gates[512 + tid] + r * hn[tid]);
            h[tid] = (1.f - zg) * nn + zg * h[tid];
        }
    }
    __syncthreads();

    // ---- gru_1: single step, input h_left, h0 = 0 (gh = b_hh_1) ----
    {
        float si = bih1[tid];
        const float* wi = Wih1 + tid * 256;
        #pragma unroll 4
        for (int k = 0; k < 256; k += 4) {
            float4 w4 = *(const float4*)(wi + k);
            si += w4.x * h[k] + w4.y * h[k+1] + w4.z * h[k+2] + w4.w * h[k+3];
        }
        float bh = bhh1[tid];
        if (tid < 512) gates[tid] = si + bh;
        else { gates[tid] = si; hn[tid & 255] = bh; }
        __syncthreads();
        if (tid < 256) {
            float r  = sigm(gates[tid]);
            float zg = sigm(gates[256 + tid]);
            float nn = tanh_fast(gates[512 + tid] + r * hn[tid]);
            h[tid] = (1.f - zg) * nn;   // + zg*0
        }
        __syncthreads();
    }

    // ---- heads (fp32 straight to out) ----
    if (tid < 256) {
        const float* w = Wmu + tid * 256;
        float s = bmu[tid];
        #pragma unroll 4
        for (int k = 0; k < 256; k += 4) {
            float4 w4 = *(const float4*)(w + k);
            s += w4.x * h[k] + w4.y * h[k+1] + w4.z * h[k+2] + w4.w * h[k+3];
        }
        out[OFF_MU + b * 256 + tid] = s;
    } else if (tid < 512) {
        const int j = tid - 256;
        const float* w = Wstd + j * 256;
        float s = bstd[j];
        #pragma unroll 4
        for (int k = 0; k < 256; k += 4) {
            float4 w4 = *(const float4*)(w + k);
            s += w4.x * h[k] + w4.y * h[k+1] + w4.z * h[k+2] + w4.w * h[k+3];
        }
        out[OFF_LV + b * 256 + j] = s;
    } else if (tid < 576) {
        const int j = tid - 512;
        const float* w = Wmean + j * 256;
        float s = bmean[j];
        #pragma unroll 4
        for (int k = 0; k < 256; k += 4) {
            float4 w4 = *(const float4*)(w + k);
            s += w4.x * h[k] + w4.y * h[k+1] + w4.z * h[k+2] + w4.w * h[k+3];
        }
        out[OFF_MEAN + b * 64 + j] = fminf(fmaxf(__expf(s), 1e-5f), 1e6f);
    } else if (tid < 640) {
        const int j = tid - 576;
        const float* w = Wdisp + j * 256;
        float s = bdisp[j];
        #pragma unroll 4
        for (int k = 0; k < 256; k += 4) {
            float4 w4 = *(const float4*)(w + k);
            s += w4.x * h[k] + w4.y * h[k+1] + w4.z * h[k+2] + w4.w * h[k+3];
        }
        float sp = (s > 20.f) ? s : log1pf(__expf(s));
        out[OFF_DISP + b * 64 + j] = fminf(fmaxf(sp, 1e-4f), 1e4f);
    }
}

// ---------------------------------------------------------------------------
// Per-series nets: 64 blocks (one per p), 1024 threads = 16 waves.
// Wave w owns gate-col slice j = w*16+ncol (all 3 gates); block owns all 64
// batch rows (4 m-tiles). W_hh[p] (bf16) read once per step -> L2-resident
// (3.15 MB per XCD across its 8 p's).
// mfma_f32_16x16x32_bf16: A[m=lane&15][k=quad*8+i] (hs LDS, ds_read_b128),
// B[k=quad*8+i][n=lane&15] = W[g*256+j][k], D[m=quad*4+r][n=lane&15].
// h carried fp32 in registers (lane owns (b=mt*16+quad*4+r, j) cells).
// ---------------------------------------------------------------------------
template <bool WS>
__global__ __launch_bounds__(1024) void nets_kernel(
    const float*          __restrict__ X,      // (64,110,64)
    const int*            __restrict__ conn,   // (64,16)
    const float*          __restrict__ Wih,    // (64,768,16)
    const float*          __restrict__ Whh_f,  // (64,768,256) fp32
    const unsigned short* __restrict__ Whh_b,  // bf16 copy in ws (WS only)
    const float*          __restrict__ bih,    // (64,768)
    const float*          __restrict__ bhh,    // (64,768)
    const float*          __restrict__ Wlin,   // (64,256)
    const float*          __restrict__ blin,   // (64)
    const float*          __restrict__ znoise, // (64,256)
    float*                __restrict__ out)
{
    const int p    = blockIdx.x;
    const int tid  = threadIdx.x;
    const int wave = tid >> 6;
    const int lane = tid & 63;
    const int quad = lane >> 4;
    const int ncol = lane & 15;
    const int j    = wave * 16 + ncol;

    __shared__ __align__(16) unsigned short hs[64][264];    // h bf16, +8 pad
    __shared__ __align__(16) unsigned short xs[64][16];     // x_t bf16
    __shared__ __align__(16) unsigned short wih_s[768][16]; // W_ih[p] bf16
    __shared__ float predw[16][64];
    __shared__ int   conn_s[16];

    // ---- stage per-p constants ----
    for (int i = tid; i < 768 * 16; i += 1024)
        (&wih_s[0][0])[i] = f2bf_fast(Wih[p * 768 * 16 + i]);
    if (tid < 16) conn_s[tid] = conn[p * 16 + tid];

    // h0 = z = mu + exp(0.5*lv)*noise (fp32 mu/lv written by encoder).
    for (int i = tid; i < 64 * 264; i += 1024) {
        int bb = i / 264, jj = i - bb * 264;
        unsigned short v = 0;
        if (jj < 256) {
            int gi = bb * 256 + jj;
            v = f2bf(out[OFF_MU + gi] + __expf(0.5f * out[OFF_LV + gi]) * znoise[gi]);
        }
        hs[bb][jj] = v;
    }
    xs[tid >> 4][tid & 15] = 0;   // l=0 input is the zero pad (64*16 = 1024)

    // fp32 recurrent state: h[mt*16+quad*4+r][j]
    float hreg[4][4];
    #pragma unroll
    for (int mt = 0; mt < 4; mt++)
        #pragma unroll
        for (int r = 0; r < 4; r++) {
            int gi = (mt * 16 + quad * 4 + r) * 256 + j;
            hreg[mt][r] = out[OFF_MU + gi] + __expf(0.5f * out[OFF_LV + gi]) * znoise[gi];
        }

    __syncthreads();

    const size_t whh_off = (size_t)p * 768 * 256;
    const unsigned short* wb_r = Whh_b + whh_off + (size_t)(j)       * 256 + quad * 8;
    const unsigned short* wb_z = Whh_b + whh_off + (size_t)(256 + j) * 256 + quad * 8;
    const unsigned short* wb_n = Whh_b + whh_off + (size_t)(512 + j) * 256 + quad * 8;
    const float* wf_r = Whh_f + whh_off + (size_t)(j)       * 256 + quad * 8;
    const float* wf_z = Whh_f + whh_off + (size_t)(256 + j) * 256 + quad * 8;
    const float* wf_n = Whh_f + whh_off + (size_t)(512 + j) * 256 + quad * 8;

    const float b_r  = bih[p * 768 + j]       + bhh[p * 768 + j];
    const float b_z  = bih[p * 768 + 256 + j] + bhh[p * 768 + 256 + j];
    const float b_in = bih[p * 768 + 512 + j];
    const float b_hn = bhh[p * 768 + 512 + j];
    const float wl   = Wlin[p * 256 + j];
    const float blin_v = blin[p];

    const bf16x8 ZERO8 = {0, 0, 0, 0, 0, 0, 0, 0};

    for (int t = 0; t < 100; t++) {
        f32x4 acc_r[4]  = {{0,0,0,0},{0,0,0,0},{0,0,0,0},{0,0,0,0}};
        f32x4 acc_z[4]  = {{0,0,0,0},{0,0,0,0},{0,0,0,0},{0,0,0,0}};
        f32x4 acc_in[4] = {{0,0,0,0},{0,0,0,0},{0,0,0,0},{0,0,0,0}};
        f32x4 acc_hn[4] = {{0,0,0,0},{0,0,0,0},{0,0,0,0},{0,0,0,0}};

        // ---- x part: K=16 zero-padded to one 32-wide k-step ----
        {
            bf16x8 a[4], br, bz, bn;
            if (quad < 2) {
                #pragma unroll
                for (int mt = 0; mt < 4; mt++)
                    a[mt] = *(const bf16x8*)&xs[mt * 16 + ncol][quad * 8];
                br = *(const bf16x8*)&wih_s[j][quad * 8];
                bz = *(const bf16x8*)&wih_s[256 + j][quad * 8];
                bn = *(const bf16x8*)&wih_s[512 + j][quad * 8];
            } else {
                a[0] = a[1] = a[2] = a[3] = ZERO8; br = bz = bn = ZERO8;
            }
            #pragma unroll
            for (int mt = 0; mt < 4; mt++) {
                acc_r[mt]  = MFMA(a[mt], br, acc_r[mt]);
                acc_z[mt]  = MFMA(a[mt], bz, acc_z[mt]);
                acc_in[mt] = MFMA(a[mt], bn, acc_in[mt]);
            }
        }

        // ---- h part: 8 k-steps over hidden 256 ----
        for (int k0 = 0; k0 < 256; k0 += 32) {
            bf16x8 br = WS ? *(const bf16x8*)(wb_r + k0) : pack8(wf_r + k0);
            bf16x8 bz = WS ? *(const bf16x8*)(wb_z + k0) : pack8(wf_z + k0);
            bf16x8 bn = WS ? *(const bf16x8*)(wb_n + k0) : pack8(wf_n + k0);
            #pragma unroll
            for (int mt = 0; mt < 4; mt++) {
                bf16x8 a = *(const bf16x8*)&hs[mt * 16 + ncol][k0 + quad * 8];
                acc_r[mt]  = MFMA(a, br, acc_r[mt]);
                acc_z[mt]  = MFMA(a, bz, acc_z[mt]);
                acc_hn[mt] = MFMA(a, bn, acc_hn[mt]);
            }
        }

        // ---- gates + state update (fp32) ----
        float pv[4][4];
        #pragma unroll
        for (int mt = 0; mt < 4; mt++)
            #pragma unroll
            for (int r = 0; r < 4; r++) {
                float rg = sigm(acc_r[mt][r] + b_r);
                float zg = sigm(acc_z[mt][r] + b_z);
                float nn = tanh_fast(acc_in[mt][r] + b_in + rg * (acc_hn[mt][r] + b_hn));
                float hv = (1.f - zg) * nn + zg * hreg[mt][r];
                hreg[mt][r] = hv;
                pv[mt][r] = fmaxf(hv, 0.f) * wl;
            }

        // reduce pred partials across the 16 ncol lanes
        #pragma unroll
        for (int mt = 0; mt < 4; mt++)
            #pragma unroll
            for (int r = 0; r < 4; r++) {
                float v = pv[mt][r];
                v += __shfl_xor(v, 1, 64);
                v += __shfl_xor(v, 2, 64);
                v += __shfl_xor(v, 4, 64);
                v += __shfl_xor(v, 8, 64);
                pv[mt][r] = v;
            }

        __syncthreads();   // all hs/xs reads of this step complete

        // write new h (bf16) for next step's MFMA
        #pragma unroll
        for (int mt = 0; mt < 4; mt++)
            #pragma unroll
            for (int r = 0; r < 4; r++)
                hs[mt * 16 + quad * 4 + r][j] = f2bf(hreg[mt][r]);

        if (ncol == 0) {
            #pragma unroll
            for (int mt = 0; mt < 4; mt++)
                #pragma unroll
                for (int r = 0; r < 4; r++)
                    predw[wave][mt * 16 + quad * 4 + r] = pv[mt][r];
        }

        // prefetch x for step t+1: seq[l] (l>=1) = X[b, 9+l, conn]
        {
            int bb = tid >> 4, k = tid & 15;
            unsigned short v = 0;
            if (t < 99) v = f2bf_fast(X[(size_t)(bb * 110 + (10 + t)) * 64 + conn_s[k]]);
            xs[bb][k] = v;
        }
        __syncthreads();   // hs/xs/predw writes visible

        if (tid < 64) {
            float s = blin_v;
            #pragma unroll
            for (int w = 0; w < 16; w++) s += predw[w][tid];
            out[(size_t)(p * 64 + tid) * 100 + t] = s;
        }
        // predw stable while tid<64 read: next predw write is after the next
        // iteration's first barrier, which readers reach only after reads.
    }
}

// ---------------------------------------------------------------------------
extern "C" void kernel_launch(void* const* d_in, const int* in_sizes, int n_in,
                              void* d_out, int out_size, void* d_ws, size_t ws_size,
                              hipStream_t stream) {
    const float* X      = (const float*)d_in[0];
    const int*   conn   = (const int*)d_in[1];
    const float* Wihl   = (const float*)d_in[2];
    const float* Whhl   = (const float*)d_in[3];
    const float* bihl   = (const float*)d_in[4];
    const float* bhhl   = (const float*)d_in[5];
    const float* Wih1   = (const float*)d_in[6];
    // d_in[7] = W_hh_1 unused: gru_1's h0 is 0, so gh reduces to b_hh_1
    const float* bih1   = (const float*)d_in[8];
    const float* bhh1   = (const float*)d_in[9];
    const float* Wmu    = (const float*)d_in[10];
    const float* bmu    = (const float*)d_in[11];
    const float* Wstd   = (const float*)d_in[12];
    const float* bstd   = (const float*)d_in[13];
    const float* Wmean  = (const float*)d_in[14];
    const float* bmean  = (const float*)d_in[15];
    const float* Wdisp  = (const float*)d_in[16];
    const float* bdisp  = (const float*)d_in[17];
    const float* Wihn   = (const float*)d_in[18];
    const float* Whhn   = (const float*)d_in[19];
    const float* bihn   = (const float*)d_in[20];
    const float* bhhn   = (const float*)d_in[21];
    const float* Wlin   = (const float*)d_in[22];
    const float* blin   = (const float*)d_in[23];
    const float* znoise = (const float*)d_in[24];

    float* out = (float*)d_out;

    const size_t WHH_ELEMS = 64ull * 768 * 256;           // 12.58M
    const bool use_ws = (ws_size >= WHH_ELEMS * 2);       // 25.2 MB bf16 copy

    if (use_ws) {
        const int n4 = (int)(WHH_ELEMS / 4);
        cvt_whh_kernel<<<(n4 + 255) / 256, 256, 0, stream>>>(
            Whhn, (unsigned short*)d_ws, n4);
    }

    encoder_kernel<<<64, 768, 0, stream>>>(
        X, Wihl, Whhl, bihl, bhhl, Wih1, bih1, bhh1,
        Wmu, bmu, Wstd, bstd, Wmean, bmean, Wdisp, bdisp, out);

    if (use_ws) {
        nets_kernel<true><<<64, 1024, 0, stream>>>(
            X, conn, Wihn, Whhn, (const unsigned short*)d_ws,
            bihn, bhhn, Wlin, blin, znoise, out);
    } else {
        nets_kernel<false><<<64, 1024, 0, stream>>>(
            X, conn, Wihn, Whhn, (const unsigned short*)nullptr,
            bihn, bhhn, Wlin, blin, znoise, out);
    }
}

// Round 10
// 828.435 us; speedup vs baseline: 52.6047x; 2.7126x over previous
//
#include <hip/hip_runtime.h>

// ---------------------------------------------------------------------------
// GRANGER — R10: register-resident-weight nets kernel.
// R9 (1.84 ms nets): 64 blocks (25% of CUs), per-step L2 weight loads
// serialized (VGPR=64 -> no loads in flight), MfmaUtil 3.9%.
// R10: grid (p=64, btile=4 of 16 rows) = 256 blocks (all CUs), 512 thr
// (8 waves = 2/SIMD, 256-VGPR cap). Each wave owns 32 gate-cols; its W_hh
// B-fragments (2 jslices x 3 gates x 8 ksteps = 192 VGPRs) are preloaded
// once; the 100-step loop has no global weight traffic.
// Output layout (fp32): pred[P,B,L,1] | log_var[B,H] | mu[B,H] | mean_[B,P]
// | disp_[B,P]
// ---------------------------------------------------------------------------

#define OFF_LV   409600
#define OFF_MU   425984
#define OFF_MEAN 442368
#define OFF_DISP 446464

typedef __attribute__((ext_vector_type(8))) short  bf16x8;
typedef __attribute__((ext_vector_type(4))) float  f32x4;

__device__ __forceinline__ float bf2f(unsigned short u) {
    union { unsigned int i; float f; } v; v.i = ((unsigned int)u) << 16; return v.f;
}
__device__ __forceinline__ unsigned short f2bf(float f) {
    union { float f; unsigned int i; } v; v.f = f;
    unsigned int x = v.i;
    return (unsigned short)((x + 0x7FFFu + ((x >> 16) & 1u)) >> 16);
}
__device__ __forceinline__ unsigned short f2bf_fast(float f) {
    return (unsigned short)((__float_as_uint(f) + 0x8000u) >> 16);
}
__device__ __forceinline__ bf16x8 pack8(const float* pf) {
    union { unsigned int u[4]; bf16x8 v; } r;
    const float4 a = *(const float4*)pf;
    const float4 b = *(const float4*)(pf + 4);
    r.u[0] = ((__float_as_uint(a.x) + 0x8000u) >> 16) | ((__float_as_uint(a.y) + 0x8000u) & 0xFFFF0000u);
    r.u[1] = ((__float_as_uint(a.z) + 0x8000u) >> 16) | ((__float_as_uint(a.w) + 0x8000u) & 0xFFFF0000u);
    r.u[2] = ((__float_as_uint(b.x) + 0x8000u) >> 16) | ((__float_as_uint(b.y) + 0x8000u) & 0xFFFF0000u);
    r.u[3] = ((__float_as_uint(b.z) + 0x8000u) >> 16) | ((__float_as_uint(b.w) + 0x8000u) & 0xFFFF0000u);
    return r.v;
}
__device__ __forceinline__ float sigm(float x) {
    return 1.0f / (1.0f + __expf(-x));
}
__device__ __forceinline__ float tanh_fast(float x) {
    return 2.0f / (1.0f + __expf(-2.0f * x)) - 1.0f;
}

#define MFMA(a, b, c) __builtin_amdgcn_mfma_f32_16x16x32_bf16((a), (b), (c), 0, 0, 0)

// ---------------------------------------------------------------------------
// W_hh fp32 -> bf16 into d_ws.
// ---------------------------------------------------------------------------
__global__ __launch_bounds__(256) void cvt_whh_kernel(
    const float* __restrict__ src, unsigned short* __restrict__ dst, int n4)
{
    int i = blockIdx.x * 256 + threadIdx.x;
    if (i < n4) {
        float4 a = ((const float4*)src)[i];
        ushort4 r;
        r.x = f2bf_fast(a.x); r.y = f2bf_fast(a.y);
        r.z = f2bf_fast(a.z); r.w = f2bf_fast(a.w);
        ((ushort4*)dst)[i] = r;
    }
}

// ---------------------------------------------------------------------------
// Encoder: one block per batch row b, 768 threads (unchanged from R9).
// ---------------------------------------------------------------------------
__global__ __launch_bounds__(768) void encoder_kernel(
    const float* __restrict__ X,
    const float* __restrict__ Wihl,   const float* __restrict__ Whhl,
    const float* __restrict__ bihl,   const float* __restrict__ bhhl,
    const float* __restrict__ Wih1,   const float* __restrict__ bih1,
    const float* __restrict__ bhh1,
    const float* __restrict__ Wmu,    const float* __restrict__ bmu,
    const float* __restrict__ Wstd,   const float* __restrict__ bstd,
    const float* __restrict__ Wmean,  const float* __restrict__ bmean,
    const float* __restrict__ Wdisp,  const float* __restrict__ bdisp,
    float* __restrict__ out)
{
    const int b   = blockIdx.x;
    const int tid = threadIdx.x;

    __shared__ float h[256];
    __shared__ float xv[64];
    __shared__ float gates[768];
    __shared__ float hn[256];

    if (tid < 256) h[tid] = 0.f;

    for (int t = 0; t < 10; t++) {
        if (tid < 64) xv[tid] = X[(b * 110 + t) * 64 + tid];
        __syncthreads();

        float si = bihl[tid];
        const float* wi = Wihl + tid * 64;
        #pragma unroll 4
        for (int k = 0; k < 64; k += 4) {
            float4 w4 = *(const float4*)(wi + k);
            si += w4.x * xv[k] + w4.y * xv[k+1] + w4.z * xv[k+2] + w4.w * xv[k+3];
        }
        float sh = bhhl[tid];
        const float* wh = Whhl + tid * 256;
        #pragma unroll 4
        for (int k = 0; k < 256; k += 4) {
            float4 w4 = *(const float4*)(wh + k);
            sh += w4.x * h[k] + w4.y * h[k+1] + w4.z * h[k+2] + w4.w * h[k+3];
        }
        if (tid < 512) gates[tid] = si + sh;
        else { gates[tid] = si; hn[tid & 255] = sh; }
        __syncthreads();

        if (tid < 256) {
            float r  = sigm(gates[tid]);
            float zg = sigm(gates[256 + tid]);
            float nn = tanh_fast(gates[512 + tid] + r * hn[tid]);
            h[tid] = (1.f - zg) * nn + zg * h[tid];
        }
    }
    __syncthreads();

    {
        float si = bih1[tid];
        const float* wi = Wih1 + tid * 256;
        #pragma unroll 4
        for (int k = 0; k < 256; k += 4) {
            float4 w4 = *(const float4*)(wi + k);
            si += w4.x * h[k] + w4.y * h[k+1] + w4.z * h[k+2] + w4.w * h[k+3];
        }
        float bh = bhh1[tid];
        if (tid < 512) gates[tid] = si + bh;
        else { gates[tid] = si; hn[tid & 255] = bh; }
        __syncthreads();
        if (tid < 256) {
            float r  = sigm(gates[tid]);
            float zg = sigm(gates[256 + tid]);
            float nn = tanh_fast(gates[512 + tid] + r * hn[tid]);
            h[tid] = (1.f - zg) * nn;
        }
        __syncthreads();
    }

    if (tid < 256) {
        const float* w = Wmu + tid * 256;
        float s = bmu[tid];
        #pragma unroll 4
        for (int k = 0; k < 256; k += 4) {
            float4 w4 = *(const float4*)(w + k);
            s += w4.x * h[k] + w4.y * h[k+1] + w4.z * h[k+2] + w4.w * h[k+3];
        }
        out[OFF_MU + b * 256 + tid] = s;
    } else if (tid < 512) {
        const int j = tid - 256;
        const float* w = Wstd + j * 256;
        float s = bstd[j];
        #pragma unroll 4
        for (int k = 0; k < 256; k += 4) {
            float4 w4 = *(const float4*)(w + k);
            s += w4.x * h[k] + w4.y * h[k+1] + w4.z * h[k+2] + w4.w * h[k+3];
        }
        out[OFF_LV + b * 256 + j] = s;
    } else if (tid < 576) {
        const int j = tid - 512;
        const float* w = Wmean + j * 256;
        float s = bmean[j];
        #pragma unroll 4
        for (int k = 0; k < 256; k += 4) {
            float4 w4 = *(const float4*)(w + k);
            s += w4.x * h[k] + w4.y * h[k+1] + w4.z * h[k+2] + w4.w * h[k+3];
        }
        out[OFF_MEAN + b * 64 + j] = fminf(fmaxf(__expf(s), 1e-5f), 1e6f);
    } else if (tid < 640) {
        const int j = tid - 576;
        const float* w = Wdisp + j * 256;
        float s = bdisp[j];
        #pragma unroll 4
        for (int k = 0; k < 256; k += 4) {
            float4 w4 = *(const float4*)(w + k);
            s += w4.x * h[k] + w4.y * h[k+1] + w4.z * h[k+2] + w4.w * h[k+3];
        }
        float sp = (s > 20.f) ? s : log1pf(__expf(s));
        out[OFF_DISP + b * 64 + j] = fminf(fmaxf(sp, 1e-4f), 1e4f);
    }
}

// ---------------------------------------------------------------------------
// Nets: grid (p=64, btile=4 of 16 rows) = 256 blocks, 512 thr = 8 waves
// (2/SIMD, VGPR cap 256). Wave w owns gate-cols j in [w*32, w*32+32)
// (2 slices of 16); W_hh B-fragments register-resident (192 VGPRs).
// mfma_f32_16x16x32_bf16 layouts (HW-verified R9):
//   A[m=lane&15][k=quad*8+i] from hs LDS; B[k][n=ncol] = W[g*256+j][k];
//   D[m=quad*4+r][n=ncol].
// ---------------------------------------------------------------------------
template <bool WS>
__global__ __launch_bounds__(512, 2) void nets_kernel(
    const float*          __restrict__ X,      // (64,110,64)
    const int*            __restrict__ conn,   // (64,16)
    const float*          __restrict__ Wih,    // (64,768,16)
    const float*          __restrict__ Whh_f,  // (64,768,256) fp32
    const unsigned short* __restrict__ Whh_b,  // bf16 copy in ws (WS only)
    const float*          __restrict__ bih,    // (64,768)
    const float*          __restrict__ bhh,    // (64,768)
    const float*          __restrict__ Wlin,   // (64,256)
    const float*          __restrict__ blin,   // (64)
    const float*          __restrict__ znoise, // (64,256)
    float*                __restrict__ out)
{
    const int p    = blockIdx.x;
    const int b0   = blockIdx.y * 16;
    const int tid  = threadIdx.x;
    const int wave = tid >> 6;
    const int lane = tid & 63;
    const int quad = lane >> 4;
    const int ncol = lane & 15;
    const int j0   = wave * 32 + ncol;       // first j-slice column
    const int j1   = j0 + 16;                // second j-slice column

    __shared__ __align__(16) unsigned short hs[16][264];    // h bf16 (+8 pad)
    __shared__ __align__(16) unsigned short xs[16][16];     // x_t bf16
    __shared__ __align__(16) unsigned short wih_s[768][16]; // W_ih[p] bf16
    __shared__ float bR[256], bZ[256], bIN[256], bHN[256], wlin_s[256];
    __shared__ float predw[8][16];
    __shared__ int   conn_s[16];

    // ---- stage per-p constants ----
    for (int i = tid; i < 768 * 16; i += 512)
        (&wih_s[0][0])[i] = f2bf_fast(Wih[p * 768 * 16 + i]);
    for (int i = tid; i < 256; i += 512) {
        bR[i]  = bih[p * 768 + i]       + bhh[p * 768 + i];
        bZ[i]  = bih[p * 768 + 256 + i] + bhh[p * 768 + 256 + i];
        bIN[i] = bih[p * 768 + 512 + i];
        bHN[i] = bhh[p * 768 + 512 + i];
        wlin_s[i] = Wlin[p * 256 + i];
    }
    if (tid < 16) conn_s[tid] = conn[p * 16 + tid];

    // h0 = z = mu + exp(0.5*lv)*noise (fp32 mu/lv from encoder).
    for (int i = tid; i < 16 * 264; i += 512) {
        int bb = i / 264, jj = i - bb * 264;
        unsigned short v = 0;
        if (jj < 256) {
            int gi = (b0 + bb) * 256 + jj;
            v = f2bf(out[OFF_MU + gi] + __expf(0.5f * out[OFF_LV + gi]) * znoise[gi]);
        }
        hs[bb][jj] = v;
    }
    if (tid < 256) xs[tid >> 4][tid & 15] = 0;   // l=0 input = zero pad

    // fp32 recurrent state: rows quad*4+r, cols j0/j1
    float hreg[2][4];
    #pragma unroll
    for (int s = 0; s < 2; s++)
        #pragma unroll
        for (int r = 0; r < 4; r++) {
            int gi = (b0 + quad * 4 + r) * 256 + (s ? j1 : j0);
            hreg[s][r] = out[OFF_MU + gi] + __expf(0.5f * out[OFF_LV + gi]) * znoise[gi];
        }

    // ---- preload W_hh B-fragments into registers (loop-invariant) ----
    const size_t whh_off = (size_t)p * 768 * 256;
    bf16x8 w_r[2][8], w_z[2][8], w_n[2][8];
    #pragma unroll
    for (int s = 0; s < 2; s++) {
        const int j = s ? j1 : j0;
        #pragma unroll
        for (int k0 = 0; k0 < 8; k0++) {
            const size_t off_r = whh_off + (size_t)(j)       * 256 + k0 * 32 + quad * 8;
            const size_t off_z = whh_off + (size_t)(256 + j) * 256 + k0 * 32 + quad * 8;
            const size_t off_n = whh_off + (size_t)(512 + j) * 256 + k0 * 32 + quad * 8;
            if (WS) {
                w_r[s][k0] = *(const bf16x8*)(Whh_b + off_r);
                w_z[s][k0] = *(const bf16x8*)(Whh_b + off_z);
                w_n[s][k0] = *(const bf16x8*)(Whh_b + off_n);
            } else {
                w_r[s][k0] = pack8(Whh_f + off_r);
                w_z[s][k0] = pack8(Whh_f + off_z);
                w_n[s][k0] = pack8(Whh_f + off_n);
            }
        }
    }

    __syncthreads();

    const float blin_v = blin[p];
    const bf16x8 ZERO8 = {0, 0, 0, 0, 0, 0, 0, 0};

    for (int t = 0; t < 100; t++) {
        f32x4 acc_r[2]  = {{0,0,0,0},{0,0,0,0}};
        f32x4 acc_z[2]  = {{0,0,0,0},{0,0,0,0}};
        f32x4 acc_in[2] = {{0,0,0,0},{0,0,0,0}};
        f32x4 acc_hn[2] = {{0,0,0,0},{0,0,0,0}};

        // ---- x part: K=16 zero-padded to one 32-wide k-step ----
        {
            bf16x8 a, br0, bz0, bn0, br1, bz1, bn1;
            if (quad < 2) {
                a   = *(const bf16x8*)&xs[ncol][quad * 8];
                br0 = *(const bf16x8*)&wih_s[j0][quad * 8];
                bz0 = *(const bf16x8*)&wih_s[256 + j0][quad * 8];
                bn0 = *(const bf16x8*)&wih_s[512 + j0][quad * 8];
                br1 = *(const bf16x8*)&wih_s[j1][quad * 8];
                bz1 = *(const bf16x8*)&wih_s[256 + j1][quad * 8];
                bn1 = *(const bf16x8*)&wih_s[512 + j1][quad * 8];
            } else {
                a = ZERO8; br0 = bz0 = bn0 = br1 = bz1 = bn1 = ZERO8;
            }
            acc_r[0]  = MFMA(a, br0, acc_r[0]);  acc_r[1]  = MFMA(a, br1, acc_r[1]);
            acc_z[0]  = MFMA(a, bz0, acc_z[0]);  acc_z[1]  = MFMA(a, bz1, acc_z[1]);
            acc_in[0] = MFMA(a, bn0, acc_in[0]); acc_in[1] = MFMA(a, bn1, acc_in[1]);
        }

        // ---- h part: 8 k-steps, weights from registers ----
        #pragma unroll
        for (int k0 = 0; k0 < 8; k0++) {
            bf16x8 a = *(const bf16x8*)&hs[ncol][k0 * 32 + quad * 8];
            acc_r[0]  = MFMA(a, w_r[0][k0], acc_r[0]);
            acc_r[1]  = MFMA(a, w_r[1][k0], acc_r[1]);
            acc_z[0]  = MFMA(a, w_z[0][k0], acc_z[0]);
            acc_z[1]  = MFMA(a, w_z[1][k0], acc_z[1]);
            acc_hn[0] = MFMA(a, w_n[0][k0], acc_hn[0]);
            acc_hn[1] = MFMA(a, w_n[1][k0], acc_hn[1]);
        }

        // ---- gates + state update (fp32); biases from LDS ----
        float pv[4];
        #pragma unroll
        for (int r = 0; r < 4; r++) pv[r] = 0.f;
        #pragma unroll
        for (int s = 0; s < 2; s++) {
            const int j = s ? j1 : j0;
            const float b_r = bR[j], b_z = bZ[j], b_in = bIN[j], b_hn = bHN[j];
            const float wl = wlin_s[j];
            #pragma unroll
            for (int r = 0; r < 4; r++) {
                float rg = sigm(acc_r[s][r] + b_r);
                float zg = sigm(acc_z[s][r] + b_z);
                float nn = tanh_fast(acc_in[s][r] + b_in + rg * (acc_hn[s][r] + b_hn));
                float hv = (1.f - zg) * nn + zg * hreg[s][r];
                hreg[s][r] = hv;
                pv[r] += fmaxf(hv, 0.f) * wl;
            }
        }

        // reduce pred partials across the 16 ncol lanes
        #pragma unroll
        for (int r = 0; r < 4; r++) {
            float v = pv[r];
            v += __shfl_xor(v, 1, 64);
            v += __shfl_xor(v, 2, 64);
            v += __shfl_xor(v, 4, 64);
            v += __shfl_xor(v, 8, 64);
            pv[r] = v;
        }

        __syncthreads();   // all hs/xs reads of this step complete

        // write new h (bf16) for next step's MFMA
        #pragma unroll
        for (int r = 0; r < 4; r++) {
            hs[quad * 4 + r][j0] = f2bf(hreg[0][r]);
            hs[quad * 4 + r][j1] = f2bf(hreg[1][r]);
        }

        if (ncol == 0) {
            #pragma unroll
            for (int r = 0; r < 4; r++)
                predw[wave][quad * 4 + r] = pv[r];
        }

        // prefetch x for step t+1: seq[l] (l>=1) = X[b, 9+l, conn]
        if (tid < 256) {
            int bb = tid >> 4, k = tid & 15;
            unsigned short v = 0;
            if (t < 99) v = f2bf_fast(X[(size_t)((b0 + bb) * 110 + (10 + t)) * 64 + conn_s[k]]);
            xs[bb][k] = v;
        }
        __syncthreads();   // hs/xs/predw writes visible

        if (tid < 16) {
            float s = blin_v;
            #pragma unroll
            for (int w = 0; w < 8; w++) s += predw[w][tid];
            out[(size_t)(p * 64 + b0 + tid) * 100 + t] = s;
        }
        // predw stable while tid<16 read: next predw write happens only
        // after the next iteration's first barrier.
    }
}

// ---------------------------------------------------------------------------
extern "C" void kernel_launch(void* const* d_in, const int* in_sizes, int n_in,
                              void* d_out, int out_size, void* d_ws, size_t ws_size,
                              hipStream_t stream) {
    const float* X      = (const float*)d_in[0];
    const int*   conn   = (const int*)d_in[1];
    const float* Wihl   = (const float*)d_in[2];
    const float* Whhl   = (const float*)d_in[3];
    const float* bihl   = (const float*)d_in[4];
    const float* bhhl   = (const float*)d_in[5];
    const float* Wih1   = (const float*)d_in[6];
    // d_in[7] = W_hh_1 unused: gru_1's h0 is 0, so gh reduces to b_hh_1
    const float* bih1   = (const float*)d_in[8];
    const float* bhh1   = (const float*)d_in[9];
    const float* Wmu    = (const float*)d_in[10];
    const float* bmu    = (const float*)d_in[11];
    const float* Wstd   = (const float*)d_in[12];
    const float* bstd   = (const float*)d_in[13];
    const float* Wmean  = (const float*)d_in[14];
    const float* bmean  = (const float*)d_in[15];
    const float* Wdisp  = (const float*)d_in[16];
    const float* bdisp  = (const float*)d_in[17];
    const float* Wihn   = (const float*)d_in[18];
    const float* Whhn   = (const float*)d_in[19];
    const float* bihn   = (const float*)d_in[20];
    const float* bhhn   = (const float*)d_in[21];
    const float* Wlin   = (const float*)d_in[22];
    const float* blin   = (const float*)d_in[23];
    const float* znoise = (const float*)d_in[24];

    float* out = (float*)d_out;

    const size_t WHH_ELEMS = 64ull * 768 * 256;           // 12.58M
    const bool use_ws = (ws_size >= WHH_ELEMS * 2);       // 25.2 MB bf16 copy

    if (use_ws) {
        const int n4 = (int)(WHH_ELEMS / 4);
        cvt_whh_kernel<<<(n4 + 255) / 256, 256, 0, stream>>>(
            Whhn, (unsigned short*)d_ws, n4);
    }

    encoder_kernel<<<64, 768, 0, stream>>>(
        X, Wihl, Whhl, bihl, bhhl, Wih1, bih1, bhh1,
        Wmu, bmu, Wstd, bstd, Wmean, bmean, Wdisp, bdisp, out);

    if (use_ws) {
        nets_kernel<true><<<dim3(64, 4), 512, 0, stream>>>(
            X, conn, Wihn, Whhn, (const unsigned short*)d_ws,
            bihn, bhhn, Wlin, blin, znoise, out);
    } else {
        nets_kernel<false><<<dim3(64, 4), 512, 0, stream>>>(
            X, conn, Wihn, Whhn, (const unsigned short*)nullptr,
            bihn, bhhn, Wlin, blin, znoise, out);
    }
}

// Round 11
// 627.357 us; speedup vs baseline: 69.4654x; 1.3205x over previous
//
#include <hip/hip_runtime.h>

// ---------------------------------------------------------------------------
// GRANGER — R11.
// 1) Encoder rewritten as single-block MFMA kernel (the old scalar encoder's
//    uncoalesced weight reads cost ~400 us).  2) nets: rcpf-based sigm/tanh
//    (plain division = ~10-op IEEE sequence) + ping-pong LDS => 1 barrier per
//    step.  Weights bf16 in d_ws (cvt for W_hh_nets, cvt2 for the rest).
// Output layout (fp32): pred[P,B,L,1] | log_var[B,H] | mu[B,H] | mean_[B,P]
// | disp_[B,P]
// ---------------------------------------------------------------------------

#define OFF_LV   409600
#define OFF_MU   425984
#define OFF_MEAN 442368
#define OFF_DISP 446464

// d_ws bf16 bank offsets (elements)
#define OFS_WHHN  0
#define OFS_WHHL  12582912
#define OFS_WIHL  12779520
#define OFS_WIH1  12828672
#define OFS_WMU   13025280
#define OFS_WSTD  13090816
#define OFS_WMEAN 13156352
#define OFS_WDISP 13172736
#define WS_TOTAL  13189120   // elems; *2 bytes = 26,378,240

typedef __attribute__((ext_vector_type(8))) short  bf16x8;
typedef __attribute__((ext_vector_type(4))) float  f32x4;

__device__ __forceinline__ float bf2f(unsigned short u) {
    union { unsigned int i; float f; } v; v.i = ((unsigned int)u) << 16; return v.f;
}
__device__ __forceinline__ unsigned short f2bf_fast(float f) {
    return (unsigned short)((__float_as_uint(f) + 0x8000u) >> 16);
}
__device__ __forceinline__ bf16x8 pack8(const float* pf) {
    union { unsigned int u[4]; bf16x8 v; } r;
    const float4 a = *(const float4*)pf;
    const float4 b = *(const float4*)(pf + 4);
    r.u[0] = ((__float_as_uint(a.x) + 0x8000u) >> 16) | ((__float_as_uint(a.y) + 0x8000u) & 0xFFFF0000u);
    r.u[1] = ((__float_as_uint(a.z) + 0x8000u) >> 16) | ((__float_as_uint(a.w) + 0x8000u) & 0xFFFF0000u);
    r.u[2] = ((__float_as_uint(b.x) + 0x8000u) >> 16) | ((__float_as_uint(b.y) + 0x8000u) & 0xFFFF0000u);
    r.u[3] = ((__float_as_uint(b.z) + 0x8000u) >> 16) | ((__float_as_uint(b.w) + 0x8000u) & 0xFFFF0000u);
    return r.v;
}
// rcpf-based, inf-safe (exp->inf => rcp(inf)=0)
__device__ __forceinline__ float sigm(float x) {
    return __builtin_amdgcn_rcpf(1.0f + __expf(-x));
}
__device__ __forceinline__ float tanh_fast(float x) {
    return 2.0f * __builtin_amdgcn_rcpf(1.0f + __expf(-2.0f * x)) - 1.0f;
}

#define MFMA(a, b, c) __builtin_amdgcn_mfma_f32_16x16x32_bf16((a), (b), (c), 0, 0, 0)

// ---------------------------------------------------------------------------
// cvt: W_hh_nets fp32 -> bf16 (12.58M elems)
// ---------------------------------------------------------------------------
__global__ __launch_bounds__(256) void cvt_whh_kernel(
    const float* __restrict__ src, unsigned short* __restrict__ dst, int n4)
{
    int i = blockIdx.x * 256 + threadIdx.x;
    if (i < n4) {
        float4 a = ((const float4*)src)[i];
        ushort4 r;
        r.x = f2bf_fast(a.x); r.y = f2bf_fast(a.y);
        r.z = f2bf_fast(a.z); r.w = f2bf_fast(a.w);
        ((ushort4*)dst)[i] = r;
    }
}

// cvt2: the 7 encoder weight tensors -> bf16 bank after W_hh_nets
__global__ __launch_bounds__(256) void cvt2_kernel(
    const float* __restrict__ Whhl, const float* __restrict__ Wihl,
    const float* __restrict__ Wih1, const float* __restrict__ Wmu,
    const float* __restrict__ Wstd, const float* __restrict__ Wmean,
    const float* __restrict__ Wdisp, unsigned short* __restrict__ ws)
{
    int i4 = blockIdx.x * 256 + threadIdx.x;
    if (i4 >= 151552) return;
    const float* src; int base;
    if      (i4 <  49152) { src = Whhl;  base = 0; }
    else if (i4 <  61440) { src = Wihl;  base = 49152; }
    else if (i4 < 110592) { src = Wih1;  base = 61440; }
    else if (i4 < 126976) { src = Wmu;   base = 110592; }
    else if (i4 < 143360) { src = Wstd;  base = 126976; }
    else if (i4 < 147456) { src = Wmean; base = 143360; }
    else                  { src = Wdisp; base = 147456; }
    float4 a = ((const float4*)src)[i4 - base];
    ushort4 r;
    r.x = f2bf_fast(a.x); r.y = f2bf_fast(a.y);
    r.z = f2bf_fast(a.z); r.w = f2bf_fast(a.w);
    ((ushort4*)ws)[OFS_WHHL / 4 + i4] = r;
}

// ---------------------------------------------------------------------------
// Encoder, MFMA: ONE block, 1024 thr = 16 waves (4 m-tiles of 16 batch rows).
// Wave w owns gate/hidden cols j = w*16+ncol (3 gate rows j, 256+j, 512+j).
// Same fragment mapping as nets (HW-verified): A[m=lane&15][k=quad*8+i],
// D[m=quad*4+r][n=ncol]. h carried fp32 in hreg[mt][r]; bf16 state in LDS.
// ---------------------------------------------------------------------------
template <bool WS>
__global__ __launch_bounds__(1024, 3) void encoder_mfma(
    const float* __restrict__ X,
    const float* __restrict__ Wihl_f, const float* __restrict__ Whhl_f,
    const float* __restrict__ bihl,   const float* __restrict__ bhhl,
    const float* __restrict__ Wih1_f, const float* __restrict__ bih1,
    const float* __restrict__ bhh1,
    const float* __restrict__ Wmu_f,  const float* __restrict__ bmu,
    const float* __restrict__ Wstd_f, const float* __restrict__ bstd,
    const float* __restrict__ Wmean_f,const float* __restrict__ bmean,
    const float* __restrict__ Wdisp_f,const float* __restrict__ bdisp,
    const unsigned short* __restrict__ ws,
    float* __restrict__ out)
{
    const int tid  = threadIdx.x;
    const int wave = tid >> 6;
    const int lane = tid & 63;
    const int quad = lane >> 4;
    const int ncol = lane & 15;
    const int j    = wave * 16 + ncol;

    __shared__ __align__(16) unsigned short hs[2][64][264];
    __shared__ __align__(16) unsigned short xs[2][64][72];
    __shared__ float bR[256], bZ[256], bIN[256], bHN[256];
    __shared__ float b1R[256], b1Z[256], b1IN[256], b1HN[256];

    for (int i = tid; i < 256; i += 1024) {
        bR[i]   = bihl[i]       + bhhl[i];
        bZ[i]   = bihl[256 + i] + bhhl[256 + i];
        bIN[i]  = bihl[512 + i];
        bHN[i]  = bhhl[512 + i];
        b1R[i]  = bih1[i]       + bhh1[i];
        b1Z[i]  = bih1[256 + i] + bhh1[256 + i];
        b1IN[i] = bih1[512 + i];
        b1HN[i] = bhh1[512 + i];
    }
    for (int i = tid; i < 64 * 264; i += 1024)
        (&hs[0][0][0])[i] = 0;                       // h0 = 0
    for (int i = tid; i < 4096; i += 1024) {
        int b = i >> 6, f = i & 63;
        xs[0][b][f] = f2bf_fast(X[(b * 110 + 0) * 64 + f]);
    }

    float hreg[4][4];
    #pragma unroll
    for (int mt = 0; mt < 4; mt++)
        #pragma unroll
        for (int r = 0; r < 4; r++) hreg[mt][r] = 0.f;

    const unsigned short* wsWIHL = ws + OFS_WIHL;
    const unsigned short* wsWHHL = ws + OFS_WHHL;
    const unsigned short* wsWIH1 = ws + OFS_WIH1;
    const unsigned short* wsWMU  = ws + OFS_WMU;
    const unsigned short* wsWSTD = ws + OFS_WSTD;
    const unsigned short* wsWMEAN= ws + OFS_WMEAN;
    const unsigned short* wsWDISP= ws + OFS_WDISP;

    __syncthreads();

    // ---- gru_left: 10 MFMA steps ----
    for (int t = 0; t < 10; t++) {
        const int cur = t & 1, nxt = cur ^ 1;
        f32x4 acc_r[4]  = {{0,0,0,0},{0,0,0,0},{0,0,0,0},{0,0,0,0}};
        f32x4 acc_z[4]  = {{0,0,0,0},{0,0,0,0},{0,0,0,0},{0,0,0,0}};
        f32x4 acc_in[4] = {{0,0,0,0},{0,0,0,0},{0,0,0,0},{0,0,0,0}};
        f32x4 acc_hn[4] = {{0,0,0,0},{0,0,0,0},{0,0,0,0},{0,0,0,0}};

        // x part: k = 64 -> 2 k-steps
        #pragma unroll
        for (int ks = 0; ks < 2; ks++) {
            const int ko = ks * 32 + quad * 8;
            bf16x8 br = WS ? *(const bf16x8*)(wsWIHL + (j)       * 64 + ko) : pack8(Wihl_f + (j)       * 64 + ko);
            bf16x8 bz = WS ? *(const bf16x8*)(wsWIHL + (256 + j) * 64 + ko) : pack8(Wihl_f + (256 + j) * 64 + ko);
            bf16x8 bn = WS ? *(const bf16x8*)(wsWIHL + (512 + j) * 64 + ko) : pack8(Wihl_f + (512 + j) * 64 + ko);
            #pragma unroll
            for (int mt = 0; mt < 4; mt++) {
                bf16x8 a = *(const bf16x8*)&xs[cur][mt * 16 + ncol][ks * 32 + quad * 8];
                acc_r[mt]  = MFMA(a, br, acc_r[mt]);
                acc_z[mt]  = MFMA(a, bz, acc_z[mt]);
                acc_in[mt] = MFMA(a, bn, acc_in[mt]);
            }
        }
        // h part: k = 256 -> 8 k-steps
        for (int ks = 0; ks < 8; ks++) {
            const int ko = ks * 32 + quad * 8;
            bf16x8 br = WS ? *(const bf16x8*)(wsWHHL + (size_t)(j)       * 256 + ko) : pack8(Whhl_f + (size_t)(j)       * 256 + ko);
            bf16x8 bz = WS ? *(const bf16x8*)(wsWHHL + (size_t)(256 + j) * 256 + ko) : pack8(Whhl_f + (size_t)(256 + j) * 256 + ko);
            bf16x8 bn = WS ? *(const bf16x8*)(wsWHHL + (size_t)(512 + j) * 256 + ko) : pack8(Whhl_f + (size_t)(512 + j) * 256 + ko);
            #pragma unroll
            for (int mt = 0; mt < 4; mt++) {
                bf16x8 a = *(const bf16x8*)&hs[cur][mt * 16 + ncol][ks * 32 + quad * 8];
                acc_r[mt]  = MFMA(a, br, acc_r[mt]);
                acc_z[mt]  = MFMA(a, bz, acc_z[mt]);
                acc_hn[mt] = MFMA(a, bn, acc_hn[mt]);
            }
        }
        // epilogue + state write
        #pragma unroll
        for (int mt = 0; mt < 4; mt++)
            #pragma unroll
            for (int r = 0; r < 4; r++) {
                float rg = sigm(acc_r[mt][r] + bR[j]);
                float zg = sigm(acc_z[mt][r] + bZ[j]);
                float nn = tanh_fast(acc_in[mt][r] + bIN[j] + rg * (acc_hn[mt][r] + bHN[j]));
                float hv = (1.f - zg) * nn + zg * hreg[mt][r];
                hreg[mt][r] = hv;
                hs[nxt][mt * 16 + quad * 4 + r][j] = f2bf_fast(hv);
            }
        // prefetch next x
        if (t < 9)
            for (int i = tid; i < 4096; i += 1024) {
                int b = i >> 6, f = i & 63;
                xs[nxt][b][f] = f2bf_fast(X[(b * 110 + (t + 1)) * 64 + f]);
            }
        __syncthreads();
    }
    // h_left now in hs[0] (t=9: nxt=0) and hreg.

    // ---- gru_1: one step, input h_left, h0 = 0 ----
    {
        f32x4 acc_r[4]  = {{0,0,0,0},{0,0,0,0},{0,0,0,0},{0,0,0,0}};
        f32x4 acc_z[4]  = {{0,0,0,0},{0,0,0,0},{0,0,0,0},{0,0,0,0}};
        f32x4 acc_in[4] = {{0,0,0,0},{0,0,0,0},{0,0,0,0},{0,0,0,0}};
        for (int ks = 0; ks < 8; ks++) {
            const int ko = ks * 32 + quad * 8;
            bf16x8 br = WS ? *(const bf16x8*)(wsWIH1 + (size_t)(j)       * 256 + ko) : pack8(Wih1_f + (size_t)(j)       * 256 + ko);
            bf16x8 bz = WS ? *(const bf16x8*)(wsWIH1 + (size_t)(256 + j) * 256 + ko) : pack8(Wih1_f + (size_t)(256 + j) * 256 + ko);
            bf16x8 bn = WS ? *(const bf16x8*)(wsWIH1 + (size_t)(512 + j) * 256 + ko) : pack8(Wih1_f + (size_t)(512 + j) * 256 + ko);
            #pragma unroll
            for (int mt = 0; mt < 4; mt++) {
                bf16x8 a = *(const bf16x8*)&hs[0][mt * 16 + ncol][ks * 32 + quad * 8];
                acc_r[mt]  = MFMA(a, br, acc_r[mt]);
                acc_z[mt]  = MFMA(a, bz, acc_z[mt]);
                acc_in[mt] = MFMA(a, bn, acc_in[mt]);
            }
        }
        #pragma unroll
        for (int mt = 0; mt < 4; mt++)
            #pragma unroll
            for (int r = 0; r < 4; r++) {
                float rg = sigm(acc_r[mt][r] + b1R[j]);
                float zg = sigm(acc_z[mt][r] + b1Z[j]);
                float nn = tanh_fast(acc_in[mt][r] + b1IN[j] + rg * b1HN[j]);
                float hv = (1.f - zg) * nn;           // + zg*0
                hs[1][mt * 16 + quad * 4 + r][j] = f2bf_fast(hv);
            }
        __syncthreads();   // h1 in hs[1]
    }

    // ---- heads: mu/lv (all waves), mean/disp (waves 0-7) ----
    {
        f32x4 acc_mu[4] = {{0,0,0,0},{0,0,0,0},{0,0,0,0},{0,0,0,0}};
        f32x4 acc_lv[4] = {{0,0,0,0},{0,0,0,0},{0,0,0,0},{0,0,0,0}};
        f32x4 acc_md[4] = {{0,0,0,0},{0,0,0,0},{0,0,0,0},{0,0,0,0}};
        const int  jm      = (wave & 3) * 16 + ncol;      // mean/disp col
        const bool do_mean = (wave < 4), do_disp = (wave >= 4 && wave < 8);

        for (int ks = 0; ks < 8; ks++) {
            const int ko = ks * 32 + quad * 8;
            bf16x8 bmu8 = WS ? *(const bf16x8*)(wsWMU  + (size_t)j * 256 + ko) : pack8(Wmu_f  + (size_t)j * 256 + ko);
            bf16x8 blv8 = WS ? *(const bf16x8*)(wsWSTD + (size_t)j * 256 + ko) : pack8(Wstd_f + (size_t)j * 256 + ko);
            bf16x8 bmd8;
            if (do_mean)      bmd8 = WS ? *(const bf16x8*)(wsWMEAN + (size_t)jm * 256 + ko) : pack8(Wmean_f + (size_t)jm * 256 + ko);
            else if (do_disp) bmd8 = WS ? *(const bf16x8*)(wsWDISP + (size_t)jm * 256 + ko) : pack8(Wdisp_f + (size_t)jm * 256 + ko);
            #pragma unroll
            for (int mt = 0; mt < 4; mt++) {
                bf16x8 a = *(const bf16x8*)&hs[1][mt * 16 + ncol][ks * 32 + quad * 8];
                acc_mu[mt] = MFMA(a, bmu8, acc_mu[mt]);
                acc_lv[mt] = MFMA(a, blv8, acc_lv[mt]);
                if (do_mean || do_disp) acc_md[mt] = MFMA(a, bmd8, acc_md[mt]);
            }
        }
        const float bmu_v = bmu[j], blv_v = bstd[j];
        #pragma unroll
        for (int mt = 0; mt < 4; mt++)
            #pragma unroll
            for (int r = 0; r < 4; r++) {
                int b = mt * 16 + quad * 4 + r;
                out[OFF_MU + b * 256 + j] = acc_mu[mt][r] + bmu_v;
                out[OFF_LV + b * 256 + j] = acc_lv[mt][r] + blv_v;
            }
        if (do_mean) {
            const float bm = bmean[jm];
            #pragma unroll
            for (int mt = 0; mt < 4; mt++)
                #pragma unroll
                for (int r = 0; r < 4; r++) {
                    int b = mt * 16 + quad * 4 + r;
                    out[OFF_MEAN + b * 64 + jm] =
                        fminf(fmaxf(__expf(acc_md[mt][r] + bm), 1e-5f), 1e6f);
                }
        } else if (do_disp) {
            const float bd = bdisp[jm];
            #pragma unroll
            for (int mt = 0; mt < 4; mt++)
                #pragma unroll
                for (int r = 0; r < 4; r++) {
                    int b = mt * 16 + quad * 4 + r;
                    float s = acc_md[mt][r] + bd;
                    float sp = (s > 20.f) ? s : log1pf(__expf(s));
                    out[OFF_DISP + b * 64 + jm] = fminf(fmaxf(sp, 1e-4f), 1e4f);
                }
        }
    }
}

// ---------------------------------------------------------------------------
// Nets: grid (p=64, btile=4 of 16 rows) = 256 blocks, 512 thr = 8 waves.
// Register-resident W_hh fragments (R10), rcpf gates, ping-pong LDS with a
// SINGLE barrier per step (barrier at end of step t orders all cur-reads and
// nxt-writes before step t+1 writes cur).
// ---------------------------------------------------------------------------
template <bool WS>
__global__ __launch_bounds__(512, 2) void nets_kernel(
    const float*          __restrict__ X,
    const int*            __restrict__ conn,
    const float*          __restrict__ Wih,
    const float*          __restrict__ Whh_f,
    const unsigned short* __restrict__ Whh_b,
    const float*          __restrict__ bih,
    const float*          __restrict__ bhh,
    const float*          __restrict__ Wlin,
    const float*          __restrict__ blin,
    const float*          __restrict__ znoise,
    float*                __restrict__ out)
{
    const int p    = blockIdx.x;
    const int b0   = blockIdx.y * 16;
    const int tid  = threadIdx.x;
    const int wave = tid >> 6;
    const int lane = tid & 63;
    const int quad = lane >> 4;
    const int ncol = lane & 15;
    const int j0   = wave * 32 + ncol;
    const int j1   = j0 + 16;

    __shared__ __align__(16) unsigned short hs[2][16][264];
    __shared__ __align__(16) unsigned short xs[2][16][16];
    __shared__ __align__(16) unsigned short wih_s[768][16];
    __shared__ float bR[256], bZ[256], bIN[256], bHN[256], wlin_s[256];
    __shared__ float predw[2][8][16];
    __shared__ int   conn_s[16];

    for (int i = tid; i < 768 * 16; i += 512)
        (&wih_s[0][0])[i] = f2bf_fast(Wih[p * 768 * 16 + i]);
    for (int i = tid; i < 256; i += 512) {
        bR[i]  = bih[p * 768 + i]       + bhh[p * 768 + i];
        bZ[i]  = bih[p * 768 + 256 + i] + bhh[p * 768 + 256 + i];
        bIN[i] = bih[p * 768 + 512 + i];
        bHN[i] = bhh[p * 768 + 512 + i];
        wlin_s[i] = Wlin[p * 256 + i];
    }
    if (tid < 16) conn_s[tid] = conn[p * 16 + tid];

    for (int i = tid; i < 16 * 264; i += 512) {
        int bb = i / 264, jj = i - bb * 264;
        unsigned short v = 0;
        if (jj < 256) {
            int gi = (b0 + bb) * 256 + jj;
            v = f2bf_fast(out[OFF_MU + gi] + __expf(0.5f * out[OFF_LV + gi]) * znoise[gi]);
        }
        hs[0][bb][jj] = v;
    }
    if (tid < 256) xs[0][tid >> 4][tid & 15] = 0;

    float hreg[2][4];
    #pragma unroll
    for (int s = 0; s < 2; s++)
        #pragma unroll
        for (int r = 0; r < 4; r++) {
            int gi = (b0 + quad * 4 + r) * 256 + (s ? j1 : j0);
            hreg[s][r] = out[OFF_MU + gi] + __expf(0.5f * out[OFF_LV + gi]) * znoise[gi];
        }

    // preload W_hh fragments (loop-invariant)
    const size_t whh_off = (size_t)p * 768 * 256;
    bf16x8 w_r[2][8], w_z[2][8], w_n[2][8];
    #pragma unroll
    for (int s = 0; s < 2; s++) {
        const int j = s ? j1 : j0;
        #pragma unroll
        for (int k0 = 0; k0 < 8; k0++) {
            const size_t o_r = whh_off + (size_t)(j)       * 256 + k0 * 32 + quad * 8;
            const size_t o_z = whh_off + (size_t)(256 + j) * 256 + k0 * 32 + quad * 8;
            const size_t o_n = whh_off + (size_t)(512 + j) * 256 + k0 * 32 + quad * 8;
            if (WS) {
                w_r[s][k0] = *(const bf16x8*)(Whh_b + o_r);
                w_z[s][k0] = *(const bf16x8*)(Whh_b + o_z);
                w_n[s][k0] = *(const bf16x8*)(Whh_b + o_n);
            } else {
                w_r[s][k0] = pack8(Whh_f + o_r);
                w_z[s][k0] = pack8(Whh_f + o_z);
                w_n[s][k0] = pack8(Whh_f + o_n);
            }
        }
    }

    __syncthreads();

    const float blin_v = blin[p];
    const bf16x8 ZERO8 = {0, 0, 0, 0, 0, 0, 0, 0};

    for (int t = 0; t < 100; t++) {
        const int cur = t & 1, nxt = cur ^ 1;
        f32x4 acc_r[2]  = {{0,0,0,0},{0,0,0,0}};
        f32x4 acc_z[2]  = {{0,0,0,0},{0,0,0,0}};
        f32x4 acc_in[2] = {{0,0,0,0},{0,0,0,0}};
        f32x4 acc_hn[2] = {{0,0,0,0},{0,0,0,0}};

        // x part (K=16 zero-padded)
        {
            bf16x8 a, br0, bz0, bn0, br1, bz1, bn1;
            if (quad < 2) {
                a   = *(const bf16x8*)&xs[cur][ncol][quad * 8];
                br0 = *(const bf16x8*)&wih_s[j0][quad * 8];
                bz0 = *(const bf16x8*)&wih_s[256 + j0][quad * 8];
                bn0 = *(const bf16x8*)&wih_s[512 + j0][quad * 8];
                br1 = *(const bf16x8*)&wih_s[j1][quad * 8];
                bz1 = *(const bf16x8*)&wih_s[256 + j1][quad * 8];
                bn1 = *(const bf16x8*)&wih_s[512 + j1][quad * 8];
            } else {
                a = ZERO8; br0 = bz0 = bn0 = br1 = bz1 = bn1 = ZERO8;
            }
            acc_r[0]  = MFMA(a, br0, acc_r[0]);  acc_r[1]  = MFMA(a, br1, acc_r[1]);
            acc_z[0]  = MFMA(a, bz0, acc_z[0]);  acc_z[1]  = MFMA(a, bz1, acc_z[1]);
            acc_in[0] = MFMA(a, bn0, acc_in[0]); acc_in[1] = MFMA(a, bn1, acc_in[1]);
        }
        // h part: weights from registers
        #pragma unroll
        for (int k0 = 0; k0 < 8; k0++) {
            bf16x8 a = *(const bf16x8*)&hs[cur][ncol][k0 * 32 + quad * 8];
            acc_r[0]  = MFMA(a, w_r[0][k0], acc_r[0]);
            acc_r[1]  = MFMA(a, w_r[1][k0], acc_r[1]);
            acc_z[0]  = MFMA(a, w_z[0][k0], acc_z[0]);
            acc_z[1]  = MFMA(a, w_z[1][k0], acc_z[1]);
            acc_hn[0] = MFMA(a, w_n[0][k0], acc_hn[0]);
            acc_hn[1] = MFMA(a, w_n[1][k0], acc_hn[1]);
        }

        // gates + state update
        float pv[4] = {0.f, 0.f, 0.f, 0.f};
        #pragma unroll
        for (int s = 0; s < 2; s++) {
            const int j = s ? j1 : j0;
            const float b_r = bR[j], b_z = bZ[j], b_in = bIN[j], b_hn = bHN[j];
            const float wl = wlin_s[j];
            #pragma unroll
            for (int r = 0; r < 4; r++) {
                float rg = sigm(acc_r[s][r] + b_r);
                float zg = sigm(acc_z[s][r] + b_z);
                float nn = tanh_fast(acc_in[s][r] + b_in + rg * (acc_hn[s][r] + b_hn));
                float hv = (1.f - zg) * nn + zg * hreg[s][r];
                hreg[s][r] = hv;
                pv[r] += fmaxf(hv, 0.f) * wl;
            }
        }
        // reduce across 16 ncol lanes
        #pragma unroll
        for (int r = 0; r < 4; r++) {
            float v = pv[r];
            v += __shfl_xor(v, 1, 64);
            v += __shfl_xor(v, 2, 64);
            v += __shfl_xor(v, 4, 64);
            v += __shfl_xor(v, 8, 64);
            pv[r] = v;
        }

        // writes into nxt buffers (no prior barrier needed: disjoint from cur)
        #pragma unroll
        for (int r = 0; r < 4; r++) {
            hs[nxt][quad * 4 + r][j0] = f2bf_fast(hreg[0][r]);
            hs[nxt][quad * 4 + r][j1] = f2bf_fast(hreg[1][r]);
        }
        if (ncol == 0) {
            #pragma unroll
            for (int r = 0; r < 4; r++)
                predw[cur][wave][quad * 4 + r] = pv[r];
        }
        if (tid < 256) {
            int bb = tid >> 4, k = tid & 15;
            unsigned short v = 0;
            if (t < 99) v = f2bf_fast(X[(size_t)((b0 + bb) * 110 + (10 + t)) * 64 + conn_s[k]]);
            xs[nxt][bb][k] = v;
        }

        __syncthreads();   // orders: cur reads & nxt/predw[cur] writes

        if (tid < 16) {
            float s = blin_v;
            #pragma unroll
            for (int w = 0; w < 8; w++) s += predw[cur][w][tid];
            out[(size_t)(p * 64 + b0 + tid) * 100 + t] = s;
        }
    }
}

// ---------------------------------------------------------------------------
extern "C" void kernel_launch(void* const* d_in, const int* in_sizes, int n_in,
                              void* d_out, int out_size, void* d_ws, size_t ws_size,
                              hipStream_t stream) {
    const float* X      = (const float*)d_in[0];
    const int*   conn   = (const int*)d_in[1];
    const float* Wihl   = (const float*)d_in[2];
    const float* Whhl   = (const float*)d_in[3];
    const float* bihl   = (const float*)d_in[4];
    const float* bhhl   = (const float*)d_in[5];
    const float* Wih1   = (const float*)d_in[6];
    // d_in[7] = W_hh_1 unused: gru_1's h0 is 0, so gh reduces to b_hh_1
    const float* bih1   = (const float*)d_in[8];
    const float* bhh1   = (const float*)d_in[9];
    const float* Wmu    = (const float*)d_in[10];
    const float* bmu    = (const float*)d_in[11];
    const float* Wstd   = (const float*)d_in[12];
    const float* bstd   = (const float*)d_in[13];
    const float* Wmean  = (const float*)d_in[14];
    const float* bmean  = (const float*)d_in[15];
    const float* Wdisp  = (const float*)d_in[16];
    const float* bdisp  = (const float*)d_in[17];
    const float* Wihn   = (const float*)d_in[18];
    const float* Whhn   = (const float*)d_in[19];
    const float* bihn   = (const float*)d_in[20];
    const float* bhhn   = (const float*)d_in[21];
    const float* Wlin   = (const float*)d_in[22];
    const float* blin   = (const float*)d_in[23];
    const float* znoise = (const float*)d_in[24];

    float* out = (float*)d_out;
    unsigned short* ws = (unsigned short*)d_ws;

    const bool use_ws = (ws_size >= (size_t)WS_TOTAL * 2);

    if (use_ws) {
        const int n4 = 12582912 / 4;
        cvt_whh_kernel<<<(n4 + 255) / 256, 256, 0, stream>>>(Whhn, ws, n4);
        cvt2_kernel<<<(151552 + 255) / 256, 256, 0, stream>>>(
            Whhl, Wihl, Wih1, Wmu, Wstd, Wmean, Wdisp, ws);
        encoder_mfma<true><<<1, 1024, 0, stream>>>(
            X, Wihl, Whhl, bihl, bhhl, Wih1, bih1, bhh1,
            Wmu, bmu, Wstd, bstd, Wmean, bmean, Wdisp, bdisp, ws, out);
        nets_kernel<true><<<dim3(64, 4), 512, 0, stream>>>(
            X, conn, Wihn, Whhn, ws + OFS_WHHN,
            bihn, bhhn, Wlin, blin, znoise, out);
    } else {
        encoder_mfma<false><<<1, 1024, 0, stream>>>(
            X, Wihl, Whhl, bihl, bhhl, Wih1, bih1, bhh1,
            Wmu, bmu, Wstd, bstd, Wmean, bmean, Wdisp, bdisp,
            (const unsigned short*)nullptr, out);
        nets_kernel<false><<<dim3(64, 4), 512, 0, stream>>>(
            X, conn, Wihn, Whhn, (const unsigned short*)nullptr,
            bihn, bhhn, Wlin, blin, znoise, out);
    }
}

// Round 12
// 573.954 us; speedup vs baseline: 75.9288x; 1.0930x over previous
//
#include <hip/hip_runtime.h>

// ---------------------------------------------------------------------------
// GRANGER — R12.
// 1) Encoder: 4 blocks x 512 thr (was 1 block x 1024 with launch_bounds(1024,3)
//    -> VGPR cap ~170 -> in-loop scratch spills on a single CU ~ 270 us).
//    Now 8 waves/block, wave owns 2 col-slices, acc pressure 32 regs, no
//    spill, weights streamed from L2 per step.
// 2) nets: x-gather issued at TOP of step (latency hidden behind compute
//    instead of draining at the barrier); RNE rounding for recurrent state
//    (absmax 0.0078 -> ~0.004).
// 3) cvt + cvt2 merged into one kernel.
// Output layout (fp32): pred[P,B,L,1] | log_var[B,H] | mu[B,H] | mean_[B,P]
// | disp_[B,P]
// ---------------------------------------------------------------------------

#define OFF_LV   409600
#define OFF_MU   425984
#define OFF_MEAN 442368
#define OFF_DISP 446464

// d_ws bf16 bank offsets (elements)
#define OFS_WHHN  0
#define OFS_WHHL  12582912
#define OFS_WIHL  12779520
#define OFS_WIH1  12828672
#define OFS_WMU   13025280
#define OFS_WSTD  13090816
#define OFS_WMEAN 13156352
#define OFS_WDISP 13172736
#define WS_TOTAL  13189120   // elems; *2 bytes = 26,378,240

typedef __attribute__((ext_vector_type(8))) short  bf16x8;
typedef __attribute__((ext_vector_type(4))) float  f32x4;

__device__ __forceinline__ float bf2f(unsigned short u) {
    union { unsigned int i; float f; } v; v.i = ((unsigned int)u) << 16; return v.f;
}
// RNE (for recurrent state / z)
__device__ __forceinline__ unsigned short f2bf(float f) {
    union { float f; unsigned int i; } v; v.f = f;
    unsigned int x = v.i;
    return (unsigned short)((x + 0x7FFFu + ((x >> 16) & 1u)) >> 16);
}
// round-half-up (weights / inputs)
__device__ __forceinline__ unsigned short f2bf_fast(float f) {
    return (unsigned short)((__float_as_uint(f) + 0x8000u) >> 16);
}
__device__ __forceinline__ bf16x8 pack8(const float* pf) {
    union { unsigned int u[4]; bf16x8 v; } r;
    const float4 a = *(const float4*)pf;
    const float4 b = *(const float4*)(pf + 4);
    r.u[0] = ((__float_as_uint(a.x) + 0x8000u) >> 16) | ((__float_as_uint(a.y) + 0x8000u) & 0xFFFF0000u);
    r.u[1] = ((__float_as_uint(a.z) + 0x8000u) >> 16) | ((__float_as_uint(a.w) + 0x8000u) & 0xFFFF0000u);
    r.u[2] = ((__float_as_uint(b.x) + 0x8000u) >> 16) | ((__float_as_uint(b.y) + 0x8000u) & 0xFFFF0000u);
    r.u[3] = ((__float_as_uint(b.z) + 0x8000u) >> 16) | ((__float_as_uint(b.w) + 0x8000u) & 0xFFFF0000u);
    return r.v;
}
// rcpf-based, inf-safe
__device__ __forceinline__ float sigm(float x) {
    return __builtin_amdgcn_rcpf(1.0f + __expf(-x));
}
__device__ __forceinline__ float tanh_fast(float x) {
    return 2.0f * __builtin_amdgcn_rcpf(1.0f + __expf(-2.0f * x)) - 1.0f;
}

#define MFMA(a, b, c) __builtin_amdgcn_mfma_f32_16x16x32_bf16((a), (b), (c), 0, 0, 0)

// ---------------------------------------------------------------------------
// cvt_all: all fp32 weight tensors -> bf16 bank in d_ws (one kernel).
// Range 1: W_hh_nets (12.58M). Range 2: the 7 encoder weight tensors.
// ---------------------------------------------------------------------------
#define CVT_N1 3145728   // 12582912/4
#define CVT_N2 151552
__global__ __launch_bounds__(256) void cvt_all_kernel(
    const float* __restrict__ Whhn,
    const float* __restrict__ Whhl, const float* __restrict__ Wihl,
    const float* __restrict__ Wih1, const float* __restrict__ Wmu,
    const float* __restrict__ Wstd, const float* __restrict__ Wmean,
    const float* __restrict__ Wdisp, unsigned short* __restrict__ ws)
{
    int i4 = blockIdx.x * 256 + threadIdx.x;
    const float* src;
    int dst4;
    if (i4 < CVT_N1) {
        src = Whhn; dst4 = i4;
    } else {
        int k = i4 - CVT_N1;
        if (k >= CVT_N2) return;
        int base;
        if      (k <  49152) { src = Whhl;  base = 0; }
        else if (k <  61440) { src = Wihl;  base = 49152; }
        else if (k < 110592) { src = Wih1;  base = 61440; }
        else if (k < 126976) { src = Wmu;   base = 110592; }
        else if (k < 143360) { src = Wstd;  base = 126976; }
        else if (k < 147456) { src = Wmean; base = 143360; }
        else                 { src = Wdisp; base = 147456; }
        src += (size_t)(k - base) * 4 - (size_t)(k - base) * 4; // keep simple below
        dst4 = OFS_WHHL / 4 + k;
        float4 a = ((const float4*)src)[k - base];
        ushort4 r;
        r.x = f2bf_fast(a.x); r.y = f2bf_fast(a.y);
        r.z = f2bf_fast(a.z); r.w = f2bf_fast(a.w);
        ((ushort4*)ws)[dst4] = r;
        return;
    }
    float4 a = ((const float4*)src)[i4];
    ushort4 r;
    r.x = f2bf_fast(a.x); r.y = f2bf_fast(a.y);
    r.z = f2bf_fast(a.z); r.w = f2bf_fast(a.w);
    ((ushort4*)ws)[dst4] = r;
}

// ---------------------------------------------------------------------------
// Encoder: 4 blocks (16 batch rows each) x 512 thr = 8 waves. Wave owns
// cols j0 = wave*32+ncol and j1 = j0+16. Weights streamed from L2 each step
// (L2-hot after step 0). Fragment mapping (HW-verified):
//   A[m=lane&15][k=quad*8+i], D[m=quad*4+r][n=ncol].
// ---------------------------------------------------------------------------
template <bool WS>
__global__ __launch_bounds__(512, 2) void encoder_mfma(
    const float* __restrict__ X,
    const float* __restrict__ Wihl_f, const float* __restrict__ Whhl_f,
    const float* __restrict__ bihl,   const float* __restrict__ bhhl,
    const float* __restrict__ Wih1_f, const float* __restrict__ bih1,
    const float* __restrict__ bhh1,
    const float* __restrict__ Wmu_f,  const float* __restrict__ bmu,
    const float* __restrict__ Wstd_f, const float* __restrict__ bstd,
    const float* __restrict__ Wmean_f,const float* __restrict__ bmean,
    const float* __restrict__ Wdisp_f,const float* __restrict__ bdisp,
    const unsigned short* __restrict__ ws,
    float* __restrict__ out)
{
    const int b0   = blockIdx.x * 16;
    const int tid  = threadIdx.x;
    const int wave = tid >> 6;
    const int lane = tid & 63;
    const int quad = lane >> 4;
    const int ncol = lane & 15;
    const int j0   = wave * 32 + ncol;
    const int j1   = j0 + 16;

    __shared__ __align__(16) unsigned short hs[2][16][264];
    __shared__ __align__(16) unsigned short xs[2][16][72];
    __shared__ float bR[256], bZ[256], bIN[256], bHN[256];
    __shared__ float b1R[256], b1Z[256], b1IN[256], b1HN[256];

    for (int i = tid; i < 256; i += 512) {
        bR[i]   = bihl[i]       + bhhl[i];
        bZ[i]   = bihl[256 + i] + bhhl[256 + i];
        bIN[i]  = bihl[512 + i];
        bHN[i]  = bhhl[512 + i];
        b1R[i]  = bih1[i]       + bhh1[i];
        b1Z[i]  = bih1[256 + i] + bhh1[256 + i];
        b1IN[i] = bih1[512 + i];
        b1HN[i] = bhh1[512 + i];
    }
    for (int i = tid; i < 16 * 264; i += 512)
        (&hs[0][0][0])[i] = 0;                       // h0 = 0
    for (int i = tid; i < 1024; i += 512) {
        int b = i >> 6, f = i & 63;
        xs[0][b][f] = f2bf_fast(X[((b0 + b) * 110 + 0) * 64 + f]);
    }

    float hreg[2][4];
    #pragma unroll
    for (int s = 0; s < 2; s++)
        #pragma unroll
        for (int r = 0; r < 4; r++) hreg[s][r] = 0.f;

    const unsigned short* wsWIHL = ws + OFS_WIHL;
    const unsigned short* wsWHHL = ws + OFS_WHHL;
    const unsigned short* wsWIH1 = ws + OFS_WIH1;
    const unsigned short* wsWMU  = ws + OFS_WMU;
    const unsigned short* wsWSTD = ws + OFS_WSTD;
    const unsigned short* wsWMEAN= ws + OFS_WMEAN;
    const unsigned short* wsWDISP= ws + OFS_WDISP;

    __syncthreads();

    // ---- gru_left: 10 MFMA steps ----
    for (int t = 0; t < 10; t++) {
        const int cur = t & 1, nxt = cur ^ 1;
        f32x4 acc_r[2]  = {{0,0,0,0},{0,0,0,0}};
        f32x4 acc_z[2]  = {{0,0,0,0},{0,0,0,0}};
        f32x4 acc_in[2] = {{0,0,0,0},{0,0,0,0}};
        f32x4 acc_hn[2] = {{0,0,0,0},{0,0,0,0}};

        // x part: k = 64 -> 2 k-steps
        #pragma unroll
        for (int ks = 0; ks < 2; ks++) {
            const int ko = ks * 32 + quad * 8;
            bf16x8 a = *(const bf16x8*)&xs[cur][ncol][ks * 32 + quad * 8];
            #pragma unroll
            for (int s = 0; s < 2; s++) {
                const int j = s ? j1 : j0;
                bf16x8 br = WS ? *(const bf16x8*)(wsWIHL + (j)       * 64 + ko) : pack8(Wihl_f + (j)       * 64 + ko);
                bf16x8 bz = WS ? *(const bf16x8*)(wsWIHL + (256 + j) * 64 + ko) : pack8(Wihl_f + (256 + j) * 64 + ko);
                bf16x8 bn = WS ? *(const bf16x8*)(wsWIHL + (512 + j) * 64 + ko) : pack8(Wihl_f + (512 + j) * 64 + ko);
                acc_r[s]  = MFMA(a, br, acc_r[s]);
                acc_z[s]  = MFMA(a, bz, acc_z[s]);
                acc_in[s] = MFMA(a, bn, acc_in[s]);
            }
        }
        // h part: k = 256 -> 8 k-steps
        #pragma unroll 2
        for (int ks = 0; ks < 8; ks++) {
            const int ko = ks * 32 + quad * 8;
            bf16x8 a = *(const bf16x8*)&hs[cur][ncol][ks * 32 + quad * 8];
            #pragma unroll
            for (int s = 0; s < 2; s++) {
                const int j = s ? j1 : j0;
                bf16x8 br = WS ? *(const bf16x8*)(wsWHHL + (size_t)(j)       * 256 + ko) : pack8(Whhl_f + (size_t)(j)       * 256 + ko);
                bf16x8 bz = WS ? *(const bf16x8*)(wsWHHL + (size_t)(256 + j) * 256 + ko) : pack8(Whhl_f + (size_t)(256 + j) * 256 + ko);
                bf16x8 bn = WS ? *(const bf16x8*)(wsWHHL + (size_t)(512 + j) * 256 + ko) : pack8(Whhl_f + (size_t)(512 + j) * 256 + ko);
                acc_r[s]  = MFMA(a, br, acc_r[s]);
                acc_z[s]  = MFMA(a, bz, acc_z[s]);
                acc_hn[s] = MFMA(a, bn, acc_hn[s]);
            }
        }
        // epilogue + state write
        #pragma unroll
        for (int s = 0; s < 2; s++) {
            const int j = s ? j1 : j0;
            #pragma unroll
            for (int r = 0; r < 4; r++) {
                float rg = sigm(acc_r[s][r] + bR[j]);
                float zg = sigm(acc_z[s][r] + bZ[j]);
                float nn = tanh_fast(acc_in[s][r] + bIN[j] + rg * (acc_hn[s][r] + bHN[j]));
                float hv = (1.f - zg) * nn + zg * hreg[s][r];
                hreg[s][r] = hv;
                hs[nxt][quad * 4 + r][j] = f2bf(hv);
            }
        }
        if (t < 9)
            for (int i = tid; i < 1024; i += 512) {
                int b = i >> 6, f = i & 63;
                xs[nxt][b][f] = f2bf_fast(X[((b0 + b) * 110 + (t + 1)) * 64 + f]);
            }
        __syncthreads();
    }
    // h_left in hs[0] (t=9: nxt=0)

    // ---- gru_1: one step, input h_left, h0 = 0 (gh = b_hh_1) ----
    {
        f32x4 acc_r[2]  = {{0,0,0,0},{0,0,0,0}};
        f32x4 acc_z[2]  = {{0,0,0,0},{0,0,0,0}};
        f32x4 acc_in[2] = {{0,0,0,0},{0,0,0,0}};
        #pragma unroll 2
        for (int ks = 0; ks < 8; ks++) {
            const int ko = ks * 32 + quad * 8;
            bf16x8 a = *(const bf16x8*)&hs[0][ncol][ks * 32 + quad * 8];
            #pragma unroll
            for (int s = 0; s < 2; s++) {
                const int j = s ? j1 : j0;
                bf16x8 br = WS ? *(const bf16x8*)(wsWIH1 + (size_t)(j)       * 256 + ko) : pack8(Wih1_f + (size_t)(j)       * 256 + ko);
                bf16x8 bz = WS ? *(const bf16x8*)(wsWIH1 + (size_t)(256 + j) * 256 + ko) : pack8(Wih1_f + (size_t)(256 + j) * 256 + ko);
                bf16x8 bn = WS ? *(const bf16x8*)(wsWIH1 + (size_t)(512 + j) * 256 + ko) : pack8(Wih1_f + (size_t)(512 + j) * 256 + ko);
                acc_r[s]  = MFMA(a, br, acc_r[s]);
                acc_z[s]  = MFMA(a, bz, acc_z[s]);
                acc_in[s] = MFMA(a, bn, acc_in[s]);
            }
        }
        #pragma unroll
        for (int s = 0; s < 2; s++) {
            const int j = s ? j1 : j0;
            #pragma unroll
            for (int r = 0; r < 4; r++) {
                float rg = sigm(acc_r[s][r] + b1R[j]);
                float zg = sigm(acc_z[s][r] + b1Z[j]);
                float nn = tanh_fast(acc_in[s][r] + b1IN[j] + rg * b1HN[j]);
                float hv = (1.f - zg) * nn;           // + zg*0
                hs[1][quad * 4 + r][j] = f2bf(hv);
            }
        }
        __syncthreads();   // h1 in hs[1]
    }

    // ---- heads ----
    {
        f32x4 acc_mu[2] = {{0,0,0,0},{0,0,0,0}};
        f32x4 acc_lv[2] = {{0,0,0,0},{0,0,0,0}};
        f32x4 acc_md[2] = {{0,0,0,0},{0,0,0,0}};
        const bool do_mean = (wave < 2), do_disp = (wave >= 2 && wave < 4);
        const int jm0 = (wave & 1) * 32 + ncol, jm1 = jm0 + 16;

        #pragma unroll 2
        for (int ks = 0; ks < 8; ks++) {
            const int ko = ks * 32 + quad * 8;
            bf16x8 a = *(const bf16x8*)&hs[1][ncol][ks * 32 + quad * 8];
            #pragma unroll
            for (int s = 0; s < 2; s++) {
                const int j = s ? j1 : j0;
                bf16x8 bmu8 = WS ? *(const bf16x8*)(wsWMU  + (size_t)j * 256 + ko) : pack8(Wmu_f  + (size_t)j * 256 + ko);
                bf16x8 blv8 = WS ? *(const bf16x8*)(wsWSTD + (size_t)j * 256 + ko) : pack8(Wstd_f + (size_t)j * 256 + ko);
                acc_mu[s] = MFMA(a, bmu8, acc_mu[s]);
                acc_lv[s] = MFMA(a, blv8, acc_lv[s]);
                if (do_mean || do_disp) {
                    const int jm = s ? jm1 : jm0;
                    bf16x8 md8;
                    if (do_mean) md8 = WS ? *(const bf16x8*)(wsWMEAN + (size_t)jm * 256 + ko) : pack8(Wmean_f + (size_t)jm * 256 + ko);
                    else         md8 = WS ? *(const bf16x8*)(wsWDISP + (size_t)jm * 256 + ko) : pack8(Wdisp_f + (size_t)jm * 256 + ko);
                    acc_md[s] = MFMA(a, md8, acc_md[s]);
                }
            }
        }
        #pragma unroll
        for (int s = 0; s < 2; s++) {
            const int j = s ? j1 : j0;
            const float bmu_v = bmu[j], blv_v = bstd[j];
            #pragma unroll
            for (int r = 0; r < 4; r++) {
                int b = b0 + quad * 4 + r;
                out[OFF_MU + b * 256 + j] = acc_mu[s][r] + bmu_v;
                out[OFF_LV + b * 256 + j] = acc_lv[s][r] + blv_v;
            }
        }
        if (do_mean) {
            #pragma unroll
            for (int s = 0; s < 2; s++) {
                const int jm = s ? jm1 : jm0;
                const float bm = bmean[jm];
                #pragma unroll
                for (int r = 0; r < 4; r++) {
                    int b = b0 + quad * 4 + r;
                    out[OFF_MEAN + b * 64 + jm] =
                        fminf(fmaxf(__expf(acc_md[s][r] + bm), 1e-5f), 1e6f);
                }
            }
        } else if (do_disp) {
            #pragma unroll
            for (int s = 0; s < 2; s++) {
                const int jm = s ? jm1 : jm0;
                const float bd = bdisp[jm];
                #pragma unroll
                for (int r = 0; r < 4; r++) {
                    int b = b0 + quad * 4 + r;
                    float v = acc_md[s][r] + bd;
                    float sp = (v > 20.f) ? v : log1pf(__expf(v));
                    out[OFF_DISP + b * 64 + jm] = fminf(fmaxf(sp, 1e-4f), 1e4f);
                }
            }
        }
    }
}

// ---------------------------------------------------------------------------
// Nets: grid (p=64, btile=4 of 16 rows) = 256 blocks, 512 thr = 8 waves.
// Register-resident W_hh fragments, rcpf gates, ping-pong LDS, single
// barrier/step, x-gather issued at TOP of step (latency hidden).
// ---------------------------------------------------------------------------
template <bool WS>
__global__ __launch_bounds__(512, 2) void nets_kernel(
    const float*          __restrict__ X,
    const int*            __restrict__ conn,
    const float*          __restrict__ Wih,
    const float*          __restrict__ Whh_f,
    const unsigned short* __restrict__ Whh_b,
    const float*          __restrict__ bih,
    const float*          __restrict__ bhh,
    const float*          __restrict__ Wlin,
    const float*          __restrict__ blin,
    const float*          __restrict__ znoise,
    float*                __restrict__ out)
{
    const int p    = blockIdx.x;
    const int b0   = blockIdx.y * 16;
    const int tid  = threadIdx.x;
    const int wave = tid >> 6;
    const int lane = tid & 63;
    const int quad = lane >> 4;
    const int ncol = lane & 15;
    const int j0   = wave * 32 + ncol;
    const int j1   = j0 + 16;

    __shared__ __align__(16) unsigned short hs[2][16][264];
    __shared__ __align__(16) unsigned short xs[2][16][16];
    __shared__ __align__(16) unsigned short wih_s[768][16];
    __shared__ float bR[256], bZ[256], bIN[256], bHN[256], wlin_s[256];
    __shared__ float predw[2][8][16];
    __shared__ int   conn_s[16];

    for (int i = tid; i < 768 * 16; i += 512)
        (&wih_s[0][0])[i] = f2bf_fast(Wih[p * 768 * 16 + i]);
    for (int i = tid; i < 256; i += 512) {
        bR[i]  = bih[p * 768 + i]       + bhh[p * 768 + i];
        bZ[i]  = bih[p * 768 + 256 + i] + bhh[p * 768 + 256 + i];
        bIN[i] = bih[p * 768 + 512 + i];
        bHN[i] = bhh[p * 768 + 512 + i];
        wlin_s[i] = Wlin[p * 256 + i];
    }
    if (tid < 16) conn_s[tid] = conn[p * 16 + tid];

    for (int i = tid; i < 16 * 264; i += 512) {
        int bb = i / 264, jj = i - bb * 264;
        unsigned short v = 0;
        if (jj < 256) {
            int gi = (b0 + bb) * 256 + jj;
            v = f2bf(out[OFF_MU + gi] + __expf(0.5f * out[OFF_LV + gi]) * znoise[gi]);
        }
        hs[0][bb][jj] = v;
    }
    if (tid < 256) xs[0][tid >> 4][tid & 15] = 0;

    float hreg[2][4];
    #pragma unroll
    for (int s = 0; s < 2; s++)
        #pragma unroll
        for (int r = 0; r < 4; r++) {
            int gi = (b0 + quad * 4 + r) * 256 + (s ? j1 : j0);
            hreg[s][r] = out[OFF_MU + gi] + __expf(0.5f * out[OFF_LV + gi]) * znoise[gi];
        }

    // preload W_hh fragments (loop-invariant)
    const size_t whh_off = (size_t)p * 768 * 256;
    bf16x8 w_r[2][8], w_z[2][8], w_n[2][8];
    #pragma unroll
    for (int s = 0; s < 2; s++) {
        const int j = s ? j1 : j0;
        #pragma unroll
        for (int k0 = 0; k0 < 8; k0++) {
            const size_t o_r = whh_off + (size_t)(j)       * 256 + k0 * 32 + quad * 8;
            const size_t o_z = whh_off + (size_t)(256 + j) * 256 + k0 * 32 + quad * 8;
            const size_t o_n = whh_off + (size_t)(512 + j) * 256 + k0 * 32 + quad * 8;
            if (WS) {
                w_r[s][k0] = *(const bf16x8*)(Whh_b + o_r);
                w_z[s][k0] = *(const bf16x8*)(Whh_b + o_z);
                w_n[s][k0] = *(const bf16x8*)(Whh_b + o_n);
            } else {
                w_r[s][k0] = pack8(Whh_f + o_r);
                w_z[s][k0] = pack8(Whh_f + o_z);
                w_n[s][k0] = pack8(Whh_f + o_n);
            }
        }
    }

    __syncthreads();

    const float blin_v = blin[p];
    const bf16x8 ZERO8 = {0, 0, 0, 0, 0, 0, 0, 0};
    const int gb = tid >> 4, gk = tid & 15;   // gather indices (tid<256)

    for (int t = 0; t < 100; t++) {
        const int cur = t & 1, nxt = cur ^ 1;

        // ---- issue x-gather for t+1 EARLY (latency hides behind compute) --
        unsigned short xv = 0;
        if (tid < 256 && t < 99)
            xv = f2bf_fast(X[(size_t)((b0 + gb) * 110 + (10 + t)) * 64 + conn_s[gk]]);

        f32x4 acc_r[2]  = {{0,0,0,0},{0,0,0,0}};
        f32x4 acc_z[2]  = {{0,0,0,0},{0,0,0,0}};
        f32x4 acc_in[2] = {{0,0,0,0},{0,0,0,0}};
        f32x4 acc_hn[2] = {{0,0,0,0},{0,0,0,0}};

        // x part (K=16 zero-padded)
        {
            bf16x8 a, br0, bz0, bn0, br1, bz1, bn1;
            if (quad < 2) {
                a   = *(const bf16x8*)&xs[cur][ncol][quad * 8];
                br0 = *(const bf16x8*)&wih_s[j0][quad * 8];
                bz0 = *(const bf16x8*)&wih_s[256 + j0][quad * 8];
                bn0 = *(const bf16x8*)&wih_s[512 + j0][quad * 8];
                br1 = *(const bf16x8*)&wih_s[j1][quad * 8];
                bz1 = *(const bf16x8*)&wih_s[256 + j1][quad * 8];
                bn1 = *(const bf16x8*)&wih_s[512 + j1][quad * 8];
            } else {
                a = ZERO8; br0 = bz0 = bn0 = br1 = bz1 = bn1 = ZERO8;
            }
            acc_r[0]  = MFMA(a, br0, acc_r[0]);  acc_r[1]  = MFMA(a, br1, acc_r[1]);
            acc_z[0]  = MFMA(a, bz0, acc_z[0]);  acc_z[1]  = MFMA(a, bz1, acc_z[1]);
            acc_in[0] = MFMA(a, bn0, acc_in[0]); acc_in[1] = MFMA(a, bn1, acc_in[1]);
        }
        // h part: weights from registers
        #pragma unroll
        for (int k0 = 0; k0 < 8; k0++) {
            bf16x8 a = *(const bf16x8*)&hs[cur][ncol][k0 * 32 + quad * 8];
            acc_r[0]  = MFMA(a, w_r[0][k0], acc_r[0]);
            acc_r[1]  = MFMA(a, w_r[1][k0], acc_r[1]);
            acc_z[0]  = MFMA(a, w_z[0][k0], acc_z[0]);
            acc_z[1]  = MFMA(a, w_z[1][k0], acc_z[1]);
            acc_hn[0] = MFMA(a, w_n[0][k0], acc_hn[0]);
            acc_hn[1] = MFMA(a, w_n[1][k0], acc_hn[1]);
        }

        // gates + state update
        float pv[4] = {0.f, 0.f, 0.f, 0.f};
        #pragma unroll
        for (int s = 0; s < 2; s++) {
            const int j = s ? j1 : j0;
            const float b_r = bR[j], b_z = bZ[j], b_in = bIN[j], b_hn = bHN[j];
            const float wl = wlin_s[j];
            #pragma unroll
            for (int r = 0; r < 4; r++) {
                float rg = sigm(acc_r[s][r] + b_r);
                float zg = sigm(acc_z[s][r] + b_z);
                float nn = tanh_fast(acc_in[s][r] + b_in + rg * (acc_hn[s][r] + b_hn));
                float hv = (1.f - zg) * nn + zg * hreg[s][r];
                hreg[s][r] = hv;
                pv[r] += fmaxf(hv, 0.f) * wl;
            }
        }
        // reduce across 16 ncol lanes
        #pragma unroll
        for (int r = 0; r < 4; r++) {
            float v = pv[r];
            v += __shfl_xor(v, 1, 64);
            v += __shfl_xor(v, 2, 64);
            v += __shfl_xor(v, 4, 64);
            v += __shfl_xor(v, 8, 64);
            pv[r] = v;
        }

        // writes into nxt buffers (disjoint from cur)
        #pragma unroll
        for (int r = 0; r < 4; r++) {
            hs[nxt][quad * 4 + r][j0] = f2bf(hreg[0][r]);
            hs[nxt][quad * 4 + r][j1] = f2bf(hreg[1][r]);
        }
        if (ncol == 0) {
            #pragma unroll
            for (int r = 0; r < 4; r++)
                predw[cur][wave][quad * 4 + r] = pv[r];
        }
        if (tid < 256) xs[nxt][gb][gk] = xv;

        __syncthreads();   // orders: cur reads & nxt/predw[cur] writes

        if (tid < 16) {
            float s = blin_v;
            #pragma unroll
            for (int w = 0; w < 8; w++) s += predw[cur][w][tid];
            out[(size_t)(p * 64 + b0 + tid) * 100 + t] = s;
        }
    }
}

// ---------------------------------------------------------------------------
extern "C" void kernel_launch(void* const* d_in, const int* in_sizes, int n_in,
                              void* d_out, int out_size, void* d_ws, size_t ws_size,
                              hipStream_t stream) {
    const float* X      = (const float*)d_in[0];
    const int*   conn   = (const int*)d_in[1];
    const float* Wihl   = (const float*)d_in[2];
    const float* Whhl   = (const float*)d_in[3];
    const float* bihl   = (const float*)d_in[4];
    const float* bhhl   = (const float*)d_in[5];
    const float* Wih1   = (const float*)d_in[6];
    // d_in[7] = W_hh_1 unused: gru_1's h0 is 0, so gh reduces to b_hh_1
    const float* bih1   = (const float*)d_in[8];
    const float* bhh1   = (const float*)d_in[9];
    const float* Wmu    = (const float*)d_in[10];
    const float* bmu    = (const float*)d_in[11];
    const float* Wstd   = (const float*)d_in[12];
    const float* bstd   = (const float*)d_in[13];
    const float* Wmean  = (const float*)d_in[14];
    const float* bmean  = (const float*)d_in[15];
    const float* Wdisp  = (const float*)d_in[16];
    const float* bdisp  = (const float*)d_in[17];
    const float* Wihn   = (const float*)d_in[18];
    const float* Whhn   = (const float*)d_in[19];
    const float* bihn   = (const float*)d_in[20];
    const float* bhhn   = (const float*)d_in[21];
    const float* Wlin   = (const float*)d_in[22];
    const float* blin   = (const float*)d_in[23];
    const float* znoise = (const float*)d_in[24];

    float* out = (float*)d_out;
    unsigned short* ws = (unsigned short*)d_ws;

    const bool use_ws = (ws_size >= (size_t)WS_TOTAL * 2);

    if (use_ws) {
        const int total4 = CVT_N1 + CVT_N2;
        cvt_all_kernel<<<(total4 + 255) / 256, 256, 0, stream>>>(
            Whhn, Whhl, Wihl, Wih1, Wmu, Wstd, Wmean, Wdisp, ws);
        encoder_mfma<true><<<4, 512, 0, stream>>>(
            X, Wihl, Whhl, bihl, bhhl, Wih1, bih1, bhh1,
            Wmu, bmu, Wstd, bstd, Wmean, bmean, Wdisp, bdisp, ws, out);
        nets_kernel<true><<<dim3(64, 4), 512, 0, stream>>>(
            X, conn, Wihn, Whhn, ws + OFS_WHHN,
            bihn, bhhn, Wlin, blin, znoise, out);
    } else {
        encoder_mfma<false><<<4, 512, 0, stream>>>(
            X, Wihl, Whhl, bihl, bhhl, Wih1, bih1, bhh1,
            Wmu, bmu, Wstd, bstd, Wmean, bmean, Wdisp, bdisp,
            (const unsigned short*)nullptr, out);
        nets_kernel<false><<<dim3(64, 4), 512, 0, stream>>>(
            X, conn, Wihn, Whhn, (const unsigned short*)nullptr,
            bihn, bhhn, Wlin, blin, znoise, out);
    }
}